// Round 5
// baseline (576.536 us; speedup 1.0000x reference)
//
#include <hip/hip_runtime.h>

#define T_SEQ 2048

typedef __attribute__((ext_vector_type(8))) short short8;
typedef __attribute__((ext_vector_type(4))) float f32x4;

__device__ __forceinline__ unsigned short f32_to_bf16(float f){
  unsigned int u = __float_as_uint(f);
  u += 0x7fffu + ((u>>16)&1u);
  return (unsigned short)(u>>16);
}

// async global->LDS, 16B per lane. LDS dest = wave-uniform base + lane*16.
__device__ __forceinline__ void g2l16(const void* g, void* l){
  __builtin_amdgcn_global_load_lds(
      (const __attribute__((address_space(1))) void*)g,
      (__attribute__((address_space(3))) void*)l, 16, 0, 0);
}

// call-free exact-GELU: Abramowitz-Stegun 7.1.26 erf, |eps|<=1.5e-7
__device__ __forceinline__ float gelu_exact(float v){
  float s = v * 0.70710678118f;
  float a = fabsf(s);
  float t = __builtin_amdgcn_rcpf(1.f + 0.3275911f*a);
  float p = t*(0.254829592f + t*(-0.284496736f + t*(1.421413741f +
            t*(-1.453152027f + t*1.061405429f))));
  float erf_a = 1.f - p*__expf(-a*a);
  float erf_s = (s < 0.f) ? -erf_a : erf_a;
  return 0.5f*v*(1.f + erf_s);
}

// ---------------------------------------------------------------- mask pack
__global__ __launch_bounds__(256) void packmask(const unsigned char* __restrict__ mraw,
                                                unsigned int* __restrict__ mbits){
  bool is_byte = (mraw[2049] == 1);
  int w = blockIdx.x*256 + threadIdx.x;          // word index, T*64 total
  int row = w >> 6, wc = w & 63;
  unsigned int bits = 0u;
  if (is_byte){
    const unsigned char* p = mraw + (size_t)row*T_SEQ + wc*32;
    #pragma unroll
    for (int j=0;j<32;j++) bits |= (p[j] ? 1u : 0u) << j;
  } else {
    const int* p = (const int*)mraw + (size_t)row*T_SEQ + wc*32;
    #pragma unroll
    for (int j=0;j<32;j++) bits |= (p[j] != 0 ? 1u : 0u) << j;
  }
  mbits[w] = bits;
}

// ------------------------------------------- BigBird column-list precompute
// Per q-tile: OR the 64 mask rows -> compacted ascending column list.
// Capacity 2048 (q-tile 31 is DENSE: mask[-1,:]=True makes the union all
// 2048 columns). Pad with -1; ncols = count rounded up to multiple of 64.
__global__ __launch_bounds__(64) void build_cols(const unsigned int* __restrict__ mbits,
                                                 int* __restrict__ cols,
                                                 int* __restrict__ ncols){
  int qt = blockIdx.x, lane = threadIdx.x;       // 64 lanes, one word each
  unsigned int w = 0;
  for (int r=0;r<64;r++) w |= mbits[(size_t)(qt*64+r)*64 + lane];
  int pc = __popc(w);
  int inc = pc;
  #pragma unroll
  for (int d=1; d<64; d<<=1){ int t = __shfl_up(inc, d, 64); if (lane>=d) inc += t; }
  int total = __shfl(inc, 63, 64);
  int idx = inc - pc;                            // exclusive prefix
  unsigned int ww = w;
  while (ww){ int b = __ffs(ww)-1; ww &= ww-1; cols[qt*2048 + idx++] = lane*32 + b; }
  for (int j = total + lane; j < 2048; j += 64) cols[qt*2048 + j] = -1;
  if (lane==0) ncols[qt] = (total + 63) & ~63;
}

// Remap mask bits onto gathered-column index space: rmask[qt][row][j>>5], 64 words/row.
__global__ __launch_bounds__(256) void build_rmask(const unsigned int* __restrict__ mbits,
                                                   const int* __restrict__ cols,
                                                   unsigned int* __restrict__ rmask){
  int qt = blockIdx.x, tid = threadIdx.x;
  for (int e = tid; e < 64*64; e += 256){
    int row = e >> 6, wj = e & 63;
    const unsigned int* mrow = mbits + (size_t)(qt*64+row)*64;
    unsigned int bits = 0;
    #pragma unroll
    for (int b=0;b<32;b++){
      int j = wj*32 + b;
      int c = cols[qt*2048 + j];
      if (c >= 0) bits |= ((mrow[c>>5] >> (c&31)) & 1u) << b;
    }
    rmask[(size_t)(qt*64+row)*64 + wj] = bits;
  }
}

// ------------------------------------------------- weight transpose+convert
__global__ __launch_bounds__(256) void transcvt(const float* __restrict__ W,
                                                unsigned short* __restrict__ WT,
                                                int K, int N){
  __shared__ float tile[32][33];
  int tx = threadIdx.x & 31, ty = threadIdx.x >> 5;
  int n0 = blockIdx.x*32, k0 = blockIdx.y*32;
  #pragma unroll
  for (int j=0;j<32;j+=8)
    tile[ty+j][tx] = W[(size_t)(k0+ty+j)*N + n0 + tx];
  __syncthreads();
  #pragma unroll
  for (int j=0;j<32;j+=8)
    WT[(size_t)(n0+ty+j)*K + k0 + tx] = f32_to_bf16(tile[tx][ty+j]);
}

// ---------------------------------------------------------------- layernorm
__global__ __launch_bounds__(256) void ln_kernel(const float* __restrict__ x,
                                                 const float* __restrict__ g,
                                                 const float* __restrict__ b,
                                                 unsigned short* __restrict__ out){
  int row = blockIdx.x, tid = threadIdx.x;
  const float* xr = x + (size_t)row*1024;
  float4 xv = *(const float4*)(xr + tid*4);
  float s  = xv.x+xv.y+xv.z+xv.w;
  float s2 = xv.x*xv.x + xv.y*xv.y + xv.z*xv.z + xv.w*xv.w;
  #pragma unroll
  for (int d=1; d<64; d<<=1){ s += __shfl_xor(s,d,64); s2 += __shfl_xor(s2,d,64); }
  __shared__ float ls[4], ls2[4];
  int wid = tid >> 6;
  if ((tid & 63) == 0){ ls[wid]=s; ls2[wid]=s2; }
  __syncthreads();
  float tot = ls[0]+ls[1]+ls[2]+ls[3];
  float tot2= ls2[0]+ls2[1]+ls2[2]+ls2[3];
  float mu  = tot * (1.f/1024.f);
  float var = tot2 * (1.f/1024.f) - mu*mu;
  float inv = rsqrtf(var + 1e-5f);
  float4 gv = *(const float4*)(g + tid*4);
  float4 bv = *(const float4*)(b + tid*4);
  unsigned short o0 = f32_to_bf16((xv.x-mu)*inv*gv.x + bv.x);
  unsigned short o1 = f32_to_bf16((xv.y-mu)*inv*gv.y + bv.y);
  unsigned short o2 = f32_to_bf16((xv.z-mu)*inv*gv.z + bv.z);
  unsigned short o3 = f32_to_bf16((xv.w-mu)*inv*gv.w + bv.w);
  unsigned short* op = out + (size_t)row*1024 + tid*4;
  op[0]=o0; op[1]=o1; op[2]=o2; op[3]=o3;
}

// ------------------------------------------------------------------- GEMM
template<bool GELU, bool BIAS, bool RES, bool OUTBF>
__global__ __launch_bounds__(256,2) void gemm_bt(const unsigned short* __restrict__ A,
                                                 const unsigned short* __restrict__ BT,
                                                 void* __restrict__ Cout,
                                                 const float* __restrict__ bias,
                                                 const float* __restrict__ res,
                                                 int M, int N, int K){
  __shared__ unsigned short sA[128*32];
  __shared__ unsigned short sB[128*32];
  int tid = threadIdx.x;
  int m0 = blockIdx.x*128, n0 = blockIdx.y*128;
  int wid = tid>>6, lane = tid&63;
  int wm = (wid>>1)*64, wn = (wid&1)*64;
  int l16 = lane&15, quad = lane>>4;

  f32x4 acc[4][4] = {};
  for (int k0=0; k0<K; k0+=32){
    #pragma unroll
    for (int i=0;i<2;i++){
      int t = i*256 + tid;
      int row = t>>2, kc = (t&3)*8;
      int wb = i*256 + (tid & ~63);
      g2l16(A  + (size_t)(m0+row)*K + k0 + kc, sA + wb*8);
      g2l16(BT + (size_t)(n0+row)*K + k0 + kc, sB + wb*8);
    }
    __syncthreads();
    short8 af[4], bf[4];
    #pragma unroll
    for (int mi=0;mi<4;mi++) af[mi] = *(const short8*)(sA + (wm+mi*16+l16)*32 + quad*8);
    #pragma unroll
    for (int ni=0;ni<4;ni++) bf[ni] = *(const short8*)(sB + (wn+ni*16+l16)*32 + quad*8);
    #pragma unroll
    for (int mi=0;mi<4;mi++)
      #pragma unroll
      for (int ni=0;ni<4;ni++)
        acc[mi][ni] = __builtin_amdgcn_mfma_f32_16x16x32_bf16(af[mi], bf[ni], acc[mi][ni], 0,0,0);
    __syncthreads();
  }
  #pragma unroll
  for (int mi=0;mi<4;mi++)
    #pragma unroll
    for (int ni=0;ni<4;ni++){
      int col = n0 + wn + ni*16 + l16;
      float bval = 0.f;
      if constexpr (BIAS) bval = bias[col];
      #pragma unroll
      for (int r=0;r<4;r++){
        int row = m0 + wm + mi*16 + quad*4 + r;
        float v = acc[mi][ni][r] + bval;
        if constexpr (GELU) v = gelu_exact(v);
        if constexpr (RES)  v += res[(size_t)row*N + col];
        if constexpr (OUTBF) ((unsigned short*)Cout)[(size_t)row*N + col] = f32_to_bf16(v);
        else                 ((float*)Cout)[(size_t)row*N + col] = v;
      }
    }
}

// 128x64-tile variant for N=1024 outputs (512 blocks -> 2 blocks/CU).
template<bool BIAS, bool RES, bool OUTBF>
__global__ __launch_bounds__(256,2) void gemm_bt_n64(const unsigned short* __restrict__ A,
                                                     const unsigned short* __restrict__ BT,
                                                     void* __restrict__ Cout,
                                                     const float* __restrict__ bias,
                                                     const float* __restrict__ res,
                                                     int M, int N, int K){
  __shared__ unsigned short sA[128*32];
  __shared__ unsigned short sB[64*32];
  int tid = threadIdx.x;
  int m0 = blockIdx.x*128, n0 = blockIdx.y*64;
  int wid = tid>>6, lane = tid&63;
  int wm = (wid>>1)*64, wn = (wid&1)*32;
  int l16 = lane&15, quad = lane>>4;

  f32x4 acc[4][2] = {};
  for (int k0=0; k0<K; k0+=32){
    #pragma unroll
    for (int i=0;i<2;i++){
      int t = i*256 + tid;
      int row = t>>2, kc = (t&3)*8;
      int wb = i*256 + (tid & ~63);
      g2l16(A + (size_t)(m0+row)*K + k0 + kc, sA + wb*8);
    }
    {
      int row = tid>>2, kc = (tid&3)*8;
      int wb = tid & ~63;
      g2l16(BT + (size_t)(n0+row)*K + k0 + kc, sB + wb*8);
    }
    __syncthreads();
    short8 af[4], bf[2];
    #pragma unroll
    for (int mi=0;mi<4;mi++) af[mi] = *(const short8*)(sA + (wm+mi*16+l16)*32 + quad*8);
    #pragma unroll
    for (int ni=0;ni<2;ni++) bf[ni] = *(const short8*)(sB + (wn+ni*16+l16)*32 + quad*8);
    #pragma unroll
    for (int mi=0;mi<4;mi++)
      #pragma unroll
      for (int ni=0;ni<2;ni++)
        acc[mi][ni] = __builtin_amdgcn_mfma_f32_16x16x32_bf16(af[mi], bf[ni], acc[mi][ni], 0,0,0);
    __syncthreads();
  }
  #pragma unroll
  for (int mi=0;mi<4;mi++)
    #pragma unroll
    for (int ni=0;ni<2;ni++){
      int col = n0 + wn + ni*16 + l16;
      float bval = 0.f;
      if constexpr (BIAS) bval = bias[col];
      #pragma unroll
      for (int r=0;r<4;r++){
        int row = m0 + wm + mi*16 + quad*4 + r;
        float v = acc[mi][ni][r] + bval;
        if constexpr (RES)  v += res[(size_t)row*N + col];
        if constexpr (OUTBF) ((unsigned short*)Cout)[(size_t)row*N + col] = f32_to_bf16(v);
        else                 ((float*)Cout)[(size_t)row*N + col] = v;
      }
    }
}

// ------------------------------------------------------------- attention
// Sparse-gather flash attention over compacted column tiles. Column indices
// read from global (L1-hot, broadcast within 8-thread groups); K/V for the
// next tile prefetched into registers during current tile's compute.
// qt = 31 - blockIdx.x so the dense qt=31 tile dispatches first.
__global__ __launch_bounds__(256,4) void attn_kernel(const unsigned short* __restrict__ qkv,
                                                     const int* __restrict__ cols,
                                                     const int* __restrict__ ncols,
                                                     const unsigned int* __restrict__ rmask,
                                                     unsigned short* __restrict__ out){
  int qt = 31 - blockIdx.x;           // heavy tile first
  int bh = blockIdx.y;                // 0..31
  int b = bh >> 4, h = bh & 15;
  int tid = threadIdx.x, wid = tid>>6, lane = tid&63;
  int l16 = lane&15, quad = lane>>4;
  const int RS = 3072;
  const size_t base = (size_t)b * T_SEQ * RS;
  int q0 = qt*64;

  __shared__ unsigned short sK [64*72];    // [krow][dim] pad 72
  __shared__ unsigned short sVt[64*72];    // [dim][krow] pad 72
  __shared__ unsigned short sX [64*72];    // raw V staging
  __shared__ unsigned short sP [4][16*72]; // per-wave P tile

  const int* gcols = cols + qt*2048;
  int niter = ncols[qt] >> 6;

  int qrow = q0 + wid*16 + l16;
  const unsigned short* qptr = qkv + base + (size_t)qrow*RS + h*64;
  short8 qf0 = *(const short8*)(qptr + quad*8);
  short8 qf1 = *(const short8*)(qptr + 32 + quad*8);

  f32x4 o[4] = {};
  float m_i[4], l_i[4];
  #pragma unroll
  for (int r=0;r<4;r++){ m_i[r] = -1e30f; l_i[r] = 0.f; }

  int krow0 = tid>>3, krow1 = 32 + (tid>>3), dc = (tid&7)*8;
  uint4 kreg[2], vreg[2];
  {
    int c0 = gcols[krow0]; if (c0 < 0) c0 = 0;
    int c1 = gcols[krow1]; if (c1 < 0) c1 = 0;
    kreg[0] = *(const uint4*)(qkv + base + (size_t)c0*RS + 1024 + h*64 + dc);
    kreg[1] = *(const uint4*)(qkv + base + (size_t)c1*RS + 1024 + h*64 + dc);
    vreg[0] = *(const uint4*)(qkv + base + (size_t)c0*RS + 2048 + h*64 + dc);
    vreg[1] = *(const uint4*)(qkv + base + (size_t)c1*RS + 2048 + h*64 + dc);
  }

  for (int kt=0; kt<niter; ++kt){
    __syncthreads();                       // prev iter's LDS readers done
    *(uint4*)(sK + krow0*72 + dc) = kreg[0];
    *(uint4*)(sK + krow1*72 + dc) = kreg[1];
    *(uint4*)(sX + krow0*72 + dc) = vreg[0];
    *(uint4*)(sX + krow1*72 + dc) = vreg[1];
    if (kt+1 < niter){                     // prefetch next tile during compute
      int c0 = gcols[(kt+1)*64 + krow0]; if (c0 < 0) c0 = 0;
      int c1 = gcols[(kt+1)*64 + krow1]; if (c1 < 0) c1 = 0;
      kreg[0] = *(const uint4*)(qkv + base + (size_t)c0*RS + 1024 + h*64 + dc);
      kreg[1] = *(const uint4*)(qkv + base + (size_t)c1*RS + 1024 + h*64 + dc);
      vreg[0] = *(const uint4*)(qkv + base + (size_t)c0*RS + 2048 + h*64 + dc);
      vreg[1] = *(const uint4*)(qkv + base + (size_t)c1*RS + 2048 + h*64 + dc);
    }
    __syncthreads();                       // sK/sX visible

    // transpose sX -> sVt (krow lane-fast => conflict-free)
    #pragma unroll
    for (int pass=0; pass<2; ++pass){
      int dg = pass*4 + wid;
      unsigned short v8[8];
      *(uint4*)v8 = *(const uint4*)(sX + lane*72 + dg*8);
      #pragma unroll
      for (int j=0;j<8;j++) sVt[(dg*8+j)*72 + lane] = v8[j];
    }

    // S = Q @ K^T
    f32x4 s[4];
    #pragma unroll
    for (int nt=0;nt<4;nt++){
      f32x4 z = {};
      short8 kb0 = *(const short8*)(sK + (nt*16+l16)*72 + quad*8);
      short8 kb1 = *(const short8*)(sK + (nt*16+l16)*72 + 32 + quad*8);
      z = __builtin_amdgcn_mfma_f32_16x16x32_bf16(qf0, kb0, z, 0,0,0);
      z = __builtin_amdgcn_mfma_f32_16x16x32_bf16(qf1, kb1, z, 0,0,0);
      s[nt] = z;
    }

    // mask (remapped bits) + scale
    float rowmax[4];
    #pragma unroll
    for (int r=0;r<4;r++){
      int rowin = wid*16 + quad*4 + r;
      const unsigned int* mrow = rmask + (size_t)(qt*64+rowin)*64 + kt*2;
      unsigned long long m64 = (unsigned long long)mrow[0] |
                               ((unsigned long long)mrow[1] << 32);
      float rm = -1e30f;
      #pragma unroll
      for (int nt=0;nt<4;nt++){
        int c6 = nt*16 + l16;
        bool ok = (m64 >> c6) & 1ull;
        float v = ok ? s[nt][r]*0.125f : -1e30f;
        s[nt][r] = v;
        rm = fmaxf(rm, v);
      }
      rowmax[r] = rm;
    }
    #pragma unroll
    for (int r=0;r<4;r++){
      float v = rowmax[r];
      #pragma unroll
      for (int d=1; d<16; d<<=1) v = fmaxf(v, __shfl_xor(v,d,64));
      rowmax[r] = v;
    }
    float alpha[4];
    #pragma unroll
    for (int r=0;r<4;r++){
      float mnew = fmaxf(m_i[r], rowmax[r]);
      alpha[r] = __expf(m_i[r] - mnew);
      m_i[r] = mnew;
    }
    #pragma unroll
    for (int nt=0;nt<4;nt++)
      #pragma unroll
      for (int r=0;r<4;r++)
        s[nt][r] = __expf(s[nt][r] - m_i[r]);
    #pragma unroll
    for (int r=0;r<4;r++){
      float v = s[0][r]+s[1][r]+s[2][r]+s[3][r];
      #pragma unroll
      for (int d=1; d<16; d<<=1) v += __shfl_xor(v,d,64);
      l_i[r] = l_i[r]*alpha[r] + v;
    }
    // P: C-layout -> per-wave LDS -> A-layout (same-wave RAW, no barrier)
    #pragma unroll
    for (int nt=0;nt<4;nt++)
      #pragma unroll
      for (int r=0;r<4;r++)
        sP[wid][(quad*4+r)*72 + nt*16 + l16] = f32_to_bf16(s[nt][r]);
    short8 p0 = *(const short8*)(sP[wid] + l16*72 + quad*8);
    short8 p1 = *(const short8*)(sP[wid] + l16*72 + 32 + quad*8);
    #pragma unroll
    for (int nt=0;nt<4;nt++)
      #pragma unroll
      for (int r=0;r<4;r++)
        o[nt][r] *= alpha[r];
    __syncthreads();                       // sVt complete
    #pragma unroll
    for (int nt=0;nt<4;nt++){
      short8 vb0 = *(const short8*)(sVt + (nt*16+l16)*72 + quad*8);
      short8 vb1 = *(const short8*)(sVt + (nt*16+l16)*72 + 32 + quad*8);
      o[nt] = __builtin_amdgcn_mfma_f32_16x16x32_bf16(p0, vb0, o[nt], 0,0,0);
      o[nt] = __builtin_amdgcn_mfma_f32_16x16x32_bf16(p1, vb1, o[nt], 0,0,0);
    }
  }
  #pragma unroll
  for (int nt=0;nt<4;nt++)
    #pragma unroll
    for (int r=0;r<4;r++){
      int row = q0 + wid*16 + quad*4 + r;
      int col = h*64 + nt*16 + l16;
      out[(size_t)(b*T_SEQ + row)*1024 + col] = f32_to_bf16(o[nt][r] / l_i[r]);
    }
}

// ---------------------------------------------------------------- launch
extern "C" void kernel_launch(void* const* d_in, const int* in_sizes, int n_in,
                              void* d_out, int out_size, void* d_ws, size_t ws_size,
                              hipStream_t stream) {
  const float* x     = (const float*)d_in[0];
  const unsigned char* mask = (const unsigned char*)d_in[1];
  const float* ln1_g = (const float*)d_in[2];
  const float* ln1_b = (const float*)d_in[3];
  const float* ln2_g = (const float*)d_in[4];
  const float* ln2_b = (const float*)d_in[5];
  const float* Wq = (const float*)d_in[6];
  const float* Wk = (const float*)d_in[7];
  const float* Wv = (const float*)d_in[8];
  const float* Wo = (const float*)d_in[9];
  const float* bo = (const float*)d_in[10];
  const float* W1 = (const float*)d_in[11];
  const float* b1 = (const float*)d_in[12];
  const float* W2 = (const float*)d_in[13];
  const float* b2 = (const float*)d_in[14];
  float* out = (float*)d_out;

  char* ws = (char*)d_ws;
  unsigned short* wqkvT = (unsigned short*)(ws);              // 3072x1024 bf16
  unsigned short* woT   = (unsigned short*)(ws + 6291456);    // 1024x1024
  unsigned short* w1T   = (unsigned short*)(ws + 8388608);    // 4096x1024
  unsigned short* w2T   = (unsigned short*)(ws + 16777216);   // 1024x4096
  unsigned short* h_bf  = (unsigned short*)(ws + 25165824);   // 4096x1024 (reused as h2)
  unsigned short* qkv   = (unsigned short*)(ws + 33554432);   // 4096x3072
  unsigned short* aout  = (unsigned short*)(ws + 58720256);   // 4096x1024
  unsigned int*   mbits = (unsigned int*)(ws + 67108864);     // 2048x64 words (512 KB)
  int*            cols  = (int*)(ws + 67633152);              // 32x2048 ints (256 KB)
  int*            ncols = (int*)(ws + 67895296);              // 32 ints
  unsigned int*   rmask = (unsigned int*)(ws + 67895424);     // 32x64x64 words (512 KB)
  unsigned short* ff1   = qkv;                                // reuse: 4096x4096

  packmask<<<512,256,0,stream>>>(mask, mbits);
  build_cols<<<32,64,0,stream>>>(mbits, cols, ncols);
  build_rmask<<<32,256,0,stream>>>(mbits, cols, rmask);
  transcvt<<<dim3(32,32),256,0,stream>>>(Wq, wqkvT,               1024, 1024);
  transcvt<<<dim3(32,32),256,0,stream>>>(Wk, wqkvT + 1024*1024,   1024, 1024);
  transcvt<<<dim3(32,32),256,0,stream>>>(Wv, wqkvT + 2*1024*1024, 1024, 1024);
  transcvt<<<dim3(32,32),256,0,stream>>>(Wo, woT,                 1024, 1024);
  transcvt<<<dim3(128,32),256,0,stream>>>(W1, w1T, 1024, 4096);
  transcvt<<<dim3(32,128),256,0,stream>>>(W2, w2T, 4096, 1024);

  ln_kernel<<<4096,256,0,stream>>>(x, ln1_g, ln1_b, h_bf);
  gemm_bt<false,false,false,true><<<dim3(32,24),256,0,stream>>>(h_bf, wqkvT, qkv, nullptr, nullptr, 4096, 3072, 1024);
  attn_kernel<<<dim3(32,32),256,0,stream>>>(qkv, cols, ncols, rmask, aout);
  gemm_bt_n64<true,true,false><<<dim3(32,16),256,0,stream>>>(aout, woT, out, bo, x, 4096, 1024, 1024);
  ln_kernel<<<4096,256,0,stream>>>(out, ln2_g, ln2_b, h_bf);
  gemm_bt<true,true,false,true><<<dim3(32,32),256,0,stream>>>(h_bf, w1T, ff1, b1, nullptr, 4096, 4096, 1024);
  gemm_bt_n64<true,true,false><<<dim3(32,16),256,0,stream>>>(ff1, w2T, out, b2, out, 4096, 1024, 4096);
}

// Round 6
// 454.915 us; speedup vs baseline: 1.2674x; 1.2674x over previous
//
#include <hip/hip_runtime.h>

#define T_SEQ 2048

typedef __attribute__((ext_vector_type(8))) short short8;
typedef __attribute__((ext_vector_type(4))) float f32x4;

__device__ __forceinline__ unsigned short f32_to_bf16(float f){
  unsigned int u = __float_as_uint(f);
  u += 0x7fffu + ((u>>16)&1u);
  return (unsigned short)(u>>16);
}
__device__ __forceinline__ float bf16_to_f32(unsigned short h){
  unsigned int u = ((unsigned int)h) << 16;
  return __uint_as_float(u);
}

// async global->LDS, 16B per lane. LDS dest = wave-uniform base + lane*16.
__device__ __forceinline__ void g2l16(const void* g, void* l){
  __builtin_amdgcn_global_load_lds(
      (const __attribute__((address_space(1))) void*)g,
      (__attribute__((address_space(3))) void*)l, 16, 0, 0);
}

// call-free exact-GELU: Abramowitz-Stegun 7.1.26 erf, |eps|<=1.5e-7
__device__ __forceinline__ float gelu_exact(float v){
  float s = v * 0.70710678118f;
  float a = fabsf(s);
  float t = __builtin_amdgcn_rcpf(1.f + 0.3275911f*a);
  float p = t*(0.254829592f + t*(-0.284496736f + t*(1.421413741f +
            t*(-1.453152027f + t*1.061405429f))));
  float erf_a = 1.f - p*__expf(-a*a);
  float erf_s = (s < 0.f) ? -erf_a : erf_a;
  return 0.5f*v*(1.f + erf_s);
}

// ---------------------------------------------------------------- mask pack
__global__ __launch_bounds__(256) void packmask(const unsigned char* __restrict__ mraw,
                                                unsigned int* __restrict__ mbits){
  bool is_byte = (mraw[2049] == 1);
  int w = blockIdx.x*256 + threadIdx.x;          // word index, T*64 total
  int row = w >> 6, wc = w & 63;
  unsigned int bits = 0u;
  if (is_byte){
    const unsigned char* p = mraw + (size_t)row*T_SEQ + wc*32;
    #pragma unroll
    for (int j=0;j<32;j++) bits |= (p[j] ? 1u : 0u) << j;
  } else {
    const int* p = (const int*)mraw + (size_t)row*T_SEQ + wc*32;
    #pragma unroll
    for (int j=0;j<32;j++) bits |= (p[j] != 0 ? 1u : 0u) << j;
  }
  mbits[w] = bits;
}

// ------------------------------------------- BigBird column-list precompute
// Per q-tile: OR the mask rows (EXCLUDING row T-1, which is dense and handled
// by attn_lastrow) -> compacted ascending column list, pad -1, ncols rounded
// up to multiple of 64. Worst case now ~sparse (<512) but keep 2048 capacity.
__global__ __launch_bounds__(64) void build_cols(const unsigned int* __restrict__ mbits,
                                                 int* __restrict__ cols,
                                                 int* __restrict__ ncols){
  int qt = blockIdx.x, lane = threadIdx.x;       // 64 lanes, one word each
  unsigned int w = 0;
  for (int r=0;r<64;r++){
    int row = qt*64 + r;
    if (row == T_SEQ-1) continue;                // dense last row excluded
    w |= mbits[(size_t)row*64 + lane];
  }
  int pc = __popc(w);
  int inc = pc;
  #pragma unroll
  for (int d=1; d<64; d<<=1){ int t = __shfl_up(inc, d, 64); if (lane>=d) inc += t; }
  int total = __shfl(inc, 63, 64);
  int idx = inc - pc;                            // exclusive prefix
  unsigned int ww = w;
  while (ww){ int b = __ffs(ww)-1; ww &= ww-1; cols[qt*2048 + idx++] = lane*32 + b; }
  for (int j = total + lane; j < 2048; j += 64) cols[qt*2048 + j] = -1;
  if (lane==0) ncols[qt] = (total + 63) & ~63;
}

// Remap mask bits onto gathered-column index space: rmask[qt][row][word],
// 64 words/row capacity; only words < ncols/32 are filled (others unread).
__global__ __launch_bounds__(256) void build_rmask(const unsigned int* __restrict__ mbits,
                                                   const int* __restrict__ cols,
                                                   const int* __restrict__ ncols,
                                                   unsigned int* __restrict__ rmask){
  int qt = blockIdx.x, tid = threadIdx.x;
  int nw = ncols[qt] >> 5;                       // words actually used
  for (int e = tid; e < 64*nw; e += 256){
    int row = e / nw, wj = e % nw;
    const unsigned int* mrow = mbits + (size_t)(qt*64+row)*64;
    unsigned int bits = 0;
    #pragma unroll
    for (int b=0;b<32;b++){
      int j = wj*32 + b;
      int c = cols[qt*2048 + j];
      if (c >= 0) bits |= ((mrow[c>>5] >> (c&31)) & 1u) << b;
    }
    rmask[(size_t)(qt*64+row)*64 + wj] = bits;
  }
}

// ------------------------------------------------- weight transpose+convert
__global__ __launch_bounds__(256) void transcvt(const float* __restrict__ W,
                                                unsigned short* __restrict__ WT,
                                                int K, int N){
  __shared__ float tile[32][33];
  int tx = threadIdx.x & 31, ty = threadIdx.x >> 5;
  int n0 = blockIdx.x*32, k0 = blockIdx.y*32;
  #pragma unroll
  for (int j=0;j<32;j+=8)
    tile[ty+j][tx] = W[(size_t)(k0+ty+j)*N + n0 + tx];
  __syncthreads();
  #pragma unroll
  for (int j=0;j<32;j+=8)
    WT[(size_t)(n0+ty+j)*K + k0 + tx] = f32_to_bf16(tile[tx][ty+j]);
}

// ---------------------------------------------------------------- layernorm
__global__ __launch_bounds__(256) void ln_kernel(const float* __restrict__ x,
                                                 const float* __restrict__ g,
                                                 const float* __restrict__ b,
                                                 unsigned short* __restrict__ out){
  int row = blockIdx.x, tid = threadIdx.x;
  const float* xr = x + (size_t)row*1024;
  float4 xv = *(const float4*)(xr + tid*4);
  float s  = xv.x+xv.y+xv.z+xv.w;
  float s2 = xv.x*xv.x + xv.y*xv.y + xv.z*xv.z + xv.w*xv.w;
  #pragma unroll
  for (int d=1; d<64; d<<=1){ s += __shfl_xor(s,d,64); s2 += __shfl_xor(s2,d,64); }
  __shared__ float ls[4], ls2[4];
  int wid = tid >> 6;
  if ((tid & 63) == 0){ ls[wid]=s; ls2[wid]=s2; }
  __syncthreads();
  float tot = ls[0]+ls[1]+ls[2]+ls[3];
  float tot2= ls2[0]+ls2[1]+ls2[2]+ls2[3];
  float mu  = tot * (1.f/1024.f);
  float var = tot2 * (1.f/1024.f) - mu*mu;
  float inv = rsqrtf(var + 1e-5f);
  float4 gv = *(const float4*)(g + tid*4);
  float4 bv = *(const float4*)(b + tid*4);
  unsigned short o0 = f32_to_bf16((xv.x-mu)*inv*gv.x + bv.x);
  unsigned short o1 = f32_to_bf16((xv.y-mu)*inv*gv.y + bv.y);
  unsigned short o2 = f32_to_bf16((xv.z-mu)*inv*gv.z + bv.z);
  unsigned short o3 = f32_to_bf16((xv.w-mu)*inv*gv.w + bv.w);
  unsigned short* op = out + (size_t)row*1024 + tid*4;
  op[0]=o0; op[1]=o1; op[2]=o2; op[3]=o3;
}

// ------------------------------------------------------------------- GEMM
template<bool GELU, bool BIAS, bool RES, bool OUTBF>
__global__ __launch_bounds__(256,2) void gemm_bt(const unsigned short* __restrict__ A,
                                                 const unsigned short* __restrict__ BT,
                                                 void* __restrict__ Cout,
                                                 const float* __restrict__ bias,
                                                 const float* __restrict__ res,
                                                 int M, int N, int K){
  __shared__ unsigned short sA[128*32];
  __shared__ unsigned short sB[128*32];
  int tid = threadIdx.x;
  int m0 = blockIdx.x*128, n0 = blockIdx.y*128;
  int wid = tid>>6, lane = tid&63;
  int wm = (wid>>1)*64, wn = (wid&1)*64;
  int l16 = lane&15, quad = lane>>4;

  f32x4 acc[4][4] = {};
  for (int k0=0; k0<K; k0+=32){
    #pragma unroll
    for (int i=0;i<2;i++){
      int t = i*256 + tid;
      int row = t>>2, kc = (t&3)*8;
      int wb = i*256 + (tid & ~63);
      g2l16(A  + (size_t)(m0+row)*K + k0 + kc, sA + wb*8);
      g2l16(BT + (size_t)(n0+row)*K + k0 + kc, sB + wb*8);
    }
    __syncthreads();
    short8 af[4], bf[4];
    #pragma unroll
    for (int mi=0;mi<4;mi++) af[mi] = *(const short8*)(sA + (wm+mi*16+l16)*32 + quad*8);
    #pragma unroll
    for (int ni=0;ni<4;ni++) bf[ni] = *(const short8*)(sB + (wn+ni*16+l16)*32 + quad*8);
    #pragma unroll
    for (int mi=0;mi<4;mi++)
      #pragma unroll
      for (int ni=0;ni<4;ni++)
        acc[mi][ni] = __builtin_amdgcn_mfma_f32_16x16x32_bf16(af[mi], bf[ni], acc[mi][ni], 0,0,0);
    __syncthreads();
  }
  #pragma unroll
  for (int mi=0;mi<4;mi++)
    #pragma unroll
    for (int ni=0;ni<4;ni++){
      int col = n0 + wn + ni*16 + l16;
      float bval = 0.f;
      if constexpr (BIAS) bval = bias[col];
      #pragma unroll
      for (int r=0;r<4;r++){
        int row = m0 + wm + mi*16 + quad*4 + r;
        float v = acc[mi][ni][r] + bval;
        if constexpr (GELU) v = gelu_exact(v);
        if constexpr (RES)  v += res[(size_t)row*N + col];
        if constexpr (OUTBF) ((unsigned short*)Cout)[(size_t)row*N + col] = f32_to_bf16(v);
        else                 ((float*)Cout)[(size_t)row*N + col] = v;
      }
    }
}

// 128x64-tile variant for N=1024 outputs (512 blocks -> 2 blocks/CU).
template<bool BIAS, bool RES, bool OUTBF>
__global__ __launch_bounds__(256,2) void gemm_bt_n64(const unsigned short* __restrict__ A,
                                                     const unsigned short* __restrict__ BT,
                                                     void* __restrict__ Cout,
                                                     const float* __restrict__ bias,
                                                     const float* __restrict__ res,
                                                     int M, int N, int K){
  __shared__ unsigned short sA[128*32];
  __shared__ unsigned short sB[64*32];
  int tid = threadIdx.x;
  int m0 = blockIdx.x*128, n0 = blockIdx.y*64;
  int wid = tid>>6, lane = tid&63;
  int wm = (wid>>1)*64, wn = (wid&1)*32;
  int l16 = lane&15, quad = lane>>4;

  f32x4 acc[4][2] = {};
  for (int k0=0; k0<K; k0+=32){
    #pragma unroll
    for (int i=0;i<2;i++){
      int t = i*256 + tid;
      int row = t>>2, kc = (t&3)*8;
      int wb = i*256 + (tid & ~63);
      g2l16(A + (size_t)(m0+row)*K + k0 + kc, sA + wb*8);
    }
    {
      int row = tid>>2, kc = (tid&3)*8;
      int wb = tid & ~63;
      g2l16(BT + (size_t)(n0+row)*K + k0 + kc, sB + wb*8);
    }
    __syncthreads();
    short8 af[4], bf[2];
    #pragma unroll
    for (int mi=0;mi<4;mi++) af[mi] = *(const short8*)(sA + (wm+mi*16+l16)*32 + quad*8);
    #pragma unroll
    for (int ni=0;ni<2;ni++) bf[ni] = *(const short8*)(sB + (wn+ni*16+l16)*32 + quad*8);
    #pragma unroll
    for (int mi=0;mi<4;mi++)
      #pragma unroll
      for (int ni=0;ni<2;ni++)
        acc[mi][ni] = __builtin_amdgcn_mfma_f32_16x16x32_bf16(af[mi], bf[ni], acc[mi][ni], 0,0,0);
    __syncthreads();
  }
  #pragma unroll
  for (int mi=0;mi<4;mi++)
    #pragma unroll
    for (int ni=0;ni<2;ni++){
      int col = n0 + wn + ni*16 + l16;
      float bval = 0.f;
      if constexpr (BIAS) bval = bias[col];
      #pragma unroll
      for (int r=0;r<4;r++){
        int row = m0 + wm + mi*16 + quad*4 + r;
        float v = acc[mi][ni][r] + bval;
        if constexpr (RES)  v += res[(size_t)row*N + col];
        if constexpr (OUTBF) ((unsigned short*)Cout)[(size_t)row*N + col] = f32_to_bf16(v);
        else                 ((float*)Cout)[(size_t)row*N + col] = v;
      }
    }
}

// ------------------------------------------------------------- attention
// Sparse-gather flash attention over compacted column tiles (row T-1
// excluded from unions -> every q-tile is sparse, niter <= ~8).
// No data prefetch (round-5 spill lesson); only next-tile index prefetch.
__global__ __launch_bounds__(256,4) void attn_kernel(const unsigned short* __restrict__ qkv,
                                                     const int* __restrict__ cols,
                                                     const int* __restrict__ ncols,
                                                     const unsigned int* __restrict__ rmask,
                                                     unsigned short* __restrict__ out){
  int qt = 31 - blockIdx.x;
  int bh = blockIdx.y;                // 0..31
  int b = bh >> 4, h = bh & 15;
  int tid = threadIdx.x, wid = tid>>6, lane = tid&63;
  int l16 = lane&15, quad = lane>>4;
  const int RS = 3072;
  const size_t base = (size_t)b * T_SEQ * RS;
  int q0 = qt*64;

  __shared__ unsigned short sK [64*72];    // [krow][dim] pad 72
  __shared__ unsigned short sVt[64*72];    // [dim][krow] pad 72
  __shared__ unsigned short sX [64*72];    // raw V staging
  __shared__ unsigned short sP [4][16*72]; // per-wave P tile

  const int* gcols = cols + qt*2048;
  int niter = ncols[qt] >> 6;

  int qrow = q0 + wid*16 + l16;
  const unsigned short* qptr = qkv + base + (size_t)qrow*RS + h*64;
  short8 qf0 = *(const short8*)(qptr + quad*8);
  short8 qf1 = *(const short8*)(qptr + 32 + quad*8);

  f32x4 o[4] = {};
  float m_i[4], l_i[4];
  #pragma unroll
  for (int r=0;r<4;r++){ m_i[r] = -1e30f; l_i[r] = 0.f; }

  int krow0 = tid>>3, krow1 = 32 + (tid>>3), dc = (tid&7)*8;
  int c0n = gcols[krow0], c1n = gcols[krow1];

  for (int kt=0; kt<niter; ++kt){
    int c0 = c0n < 0 ? 0 : c0n;
    int c1 = c1n < 0 ? 0 : c1n;
    const unsigned short* p0 = qkv + base + (size_t)c0*RS + 1024 + h*64 + dc;
    const unsigned short* p1 = qkv + base + (size_t)c1*RS + 1024 + h*64 + dc;
    uint4 k0 = *(const uint4*)p0;
    uint4 k1 = *(const uint4*)p1;
    uint4 v0 = *(const uint4*)(p0 + 1024);
    uint4 v1 = *(const uint4*)(p1 + 1024);
    if (kt+1 < niter){
      c0n = gcols[(kt+1)*64 + krow0];
      c1n = gcols[(kt+1)*64 + krow1];
    }
    __syncthreads();                       // prev iter's LDS readers done
    *(uint4*)(sK + krow0*72 + dc) = k0;
    *(uint4*)(sK + krow1*72 + dc) = k1;
    *(uint4*)(sX + krow0*72 + dc) = v0;
    *(uint4*)(sX + krow1*72 + dc) = v1;
    __syncthreads();                       // sK/sX visible

    // transpose sX -> sVt (krow lane-fast => conflict-free)
    #pragma unroll
    for (int pass=0; pass<2; ++pass){
      int dg = pass*4 + wid;
      unsigned short v8[8];
      *(uint4*)v8 = *(const uint4*)(sX + lane*72 + dg*8);
      #pragma unroll
      for (int j=0;j<8;j++) sVt[(dg*8+j)*72 + lane] = v8[j];
    }

    // S = Q @ K^T
    f32x4 s[4];
    #pragma unroll
    for (int nt=0;nt<4;nt++){
      f32x4 z = {};
      short8 kb0 = *(const short8*)(sK + (nt*16+l16)*72 + quad*8);
      short8 kb1 = *(const short8*)(sK + (nt*16+l16)*72 + 32 + quad*8);
      z = __builtin_amdgcn_mfma_f32_16x16x32_bf16(qf0, kb0, z, 0,0,0);
      z = __builtin_amdgcn_mfma_f32_16x16x32_bf16(qf1, kb1, z, 0,0,0);
      s[nt] = z;
    }

    // mask (remapped bits) + scale
    float rowmax[4];
    #pragma unroll
    for (int r=0;r<4;r++){
      int rowin = wid*16 + quad*4 + r;
      const unsigned int* mrow = rmask + (size_t)(qt*64+rowin)*64 + kt*2;
      unsigned long long m64 = (unsigned long long)mrow[0] |
                               ((unsigned long long)mrow[1] << 32);
      float rm = -1e30f;
      #pragma unroll
      for (int nt=0;nt<4;nt++){
        int c6 = nt*16 + l16;
        bool ok = (m64 >> c6) & 1ull;
        float v = ok ? s[nt][r]*0.125f : -1e30f;
        s[nt][r] = v;
        rm = fmaxf(rm, v);
      }
      rowmax[r] = rm;
    }
    #pragma unroll
    for (int r=0;r<4;r++){
      float v = rowmax[r];
      #pragma unroll
      for (int d=1; d<16; d<<=1) v = fmaxf(v, __shfl_xor(v,d,64));
      rowmax[r] = v;
    }
    float alpha[4];
    #pragma unroll
    for (int r=0;r<4;r++){
      float mnew = fmaxf(m_i[r], rowmax[r]);
      alpha[r] = __expf(m_i[r] - mnew);
      m_i[r] = mnew;
    }
    #pragma unroll
    for (int nt=0;nt<4;nt++)
      #pragma unroll
      for (int r=0;r<4;r++)
        s[nt][r] = __expf(s[nt][r] - m_i[r]);
    #pragma unroll
    for (int r=0;r<4;r++){
      float v = s[0][r]+s[1][r]+s[2][r]+s[3][r];
      #pragma unroll
      for (int d=1; d<16; d<<=1) v += __shfl_xor(v,d,64);
      l_i[r] = l_i[r]*alpha[r] + v;
    }
    // P: C-layout -> per-wave LDS -> A-layout (same-wave RAW, no barrier)
    #pragma unroll
    for (int nt=0;nt<4;nt++)
      #pragma unroll
      for (int r=0;r<4;r++)
        sP[wid][(quad*4+r)*72 + nt*16 + l16] = f32_to_bf16(s[nt][r]);
    short8 p0f = *(const short8*)(sP[wid] + l16*72 + quad*8);
    short8 p1f = *(const short8*)(sP[wid] + l16*72 + 32 + quad*8);
    #pragma unroll
    for (int nt=0;nt<4;nt++)
      #pragma unroll
      for (int r=0;r<4;r++)
        o[nt][r] *= alpha[r];
    __syncthreads();                       // sVt complete
    #pragma unroll
    for (int nt=0;nt<4;nt++){
      short8 vb0 = *(const short8*)(sVt + (nt*16+l16)*72 + quad*8);
      short8 vb1 = *(const short8*)(sVt + (nt*16+l16)*72 + 32 + quad*8);
      o[nt] = __builtin_amdgcn_mfma_f32_16x16x32_bf16(p0f, vb0, o[nt], 0,0,0);
      o[nt] = __builtin_amdgcn_mfma_f32_16x16x32_bf16(p1f, vb1, o[nt], 0,0,0);
    }
  }
  #pragma unroll
  for (int nt=0;nt<4;nt++)
    #pragma unroll
    for (int r=0;r<4;r++){
      int row = q0 + wid*16 + quad*4 + r;
      int col = h*64 + nt*16 + l16;
      out[(size_t)(b*T_SEQ + row)*1024 + col] = f32_to_bf16(o[nt][r] / l_i[r]);
    }
}

// ---------------------------------------------------- dense last-row attn
// Row T-1 attends to all 2048 keys. One block per (b,h); exact two-pass
// softmax, scores staged in LDS. Overwrites aout row T-1 (launched after
// attn_kernel, which writes garbage there).
__global__ __launch_bounds__(256,1) void attn_lastrow(const unsigned short* __restrict__ qkv,
                                                      unsigned short* __restrict__ out){
  int b = blockIdx.x, h = blockIdx.y;
  int tid = threadIdx.x, lane = tid & 63, wid = tid >> 6;
  const int RS = 3072;
  const size_t base = (size_t)b * T_SEQ * RS;

  __shared__ float sS[2048];
  __shared__ float sRed[4];
  __shared__ float sO[4][64];
  __shared__ unsigned short sQ[64];

  if (tid < 8)
    *(uint4*)(sQ + tid*8) = *(const uint4*)(qkv + base + (size_t)(T_SEQ-1)*RS + h*64 + tid*8);
  __syncthreads();
  float qf[64];
  #pragma unroll
  for (int j=0;j<64;j++) qf[j] = bf16_to_f32(sQ[j]);

  // pass 1: scores + local max
  float lmax = -1e30f;
  for (int k = tid; k < T_SEQ; k += 256){
    const unsigned short* kp = qkv + base + (size_t)k*RS + 1024 + h*64;
    float acc = 0.f;
    #pragma unroll
    for (int c=0;c<8;c++){
      unsigned short kk[8];
      *(uint4*)kk = *(const uint4*)(kp + c*8);
      #pragma unroll
      for (int j=0;j<8;j++) acc += qf[c*8+j]*bf16_to_f32(kk[j]);
    }
    float sv = acc * 0.125f;
    sS[k] = sv;
    lmax = fmaxf(lmax, sv);
  }
  #pragma unroll
  for (int d=1; d<64; d<<=1) lmax = fmaxf(lmax, __shfl_xor(lmax, d, 64));
  if (lane == 0) sRed[wid] = lmax;
  __syncthreads();
  float m = fmaxf(fmaxf(sRed[0],sRed[1]), fmaxf(sRed[2],sRed[3]));
  // exponentiate + local sum
  float lsum = 0.f;
  for (int k = tid; k < T_SEQ; k += 256){
    float p = __expf(sS[k] - m);
    sS[k] = p;
    lsum += p;
  }
  #pragma unroll
  for (int d=1; d<64; d<<=1) lsum += __shfl_xor(lsum, d, 64);
  __syncthreads();
  if (lane == 0) sRed[wid] = lsum;
  __syncthreads();
  float l = sRed[0]+sRed[1]+sRed[2]+sRed[3];

  // pass 2: o[d] = sum_k p[k] * V[k][d], key range split by wave
  int d = tid & 63;
  int chunk = wid;
  float oacc = 0.f;
  const unsigned short* vp = qkv + base + 2048 + h*64 + d;
  #pragma unroll 4
  for (int k = chunk*512; k < chunk*512 + 512; ++k)
    oacc += sS[k] * bf16_to_f32(vp[(size_t)k*RS]);
  sO[chunk][d] = oacc;
  __syncthreads();
  if (wid == 0){
    float ov = (sO[0][d]+sO[1][d]+sO[2][d]+sO[3][d]) / l;
    out[(size_t)(b*T_SEQ + T_SEQ-1)*1024 + h*64 + d] = f32_to_bf16(ov);
  }
}

// ---------------------------------------------------------------- launch
extern "C" void kernel_launch(void* const* d_in, const int* in_sizes, int n_in,
                              void* d_out, int out_size, void* d_ws, size_t ws_size,
                              hipStream_t stream) {
  const float* x     = (const float*)d_in[0];
  const unsigned char* mask = (const unsigned char*)d_in[1];
  const float* ln1_g = (const float*)d_in[2];
  const float* ln1_b = (const float*)d_in[3];
  const float* ln2_g = (const float*)d_in[4];
  const float* ln2_b = (const float*)d_in[5];
  const float* Wq = (const float*)d_in[6];
  const float* Wk = (const float*)d_in[7];
  const float* Wv = (const float*)d_in[8];
  const float* Wo = (const float*)d_in[9];
  const float* bo = (const float*)d_in[10];
  const float* W1 = (const float*)d_in[11];
  const float* b1 = (const float*)d_in[12];
  const float* W2 = (const float*)d_in[13];
  const float* b2 = (const float*)d_in[14];
  float* out = (float*)d_out;

  char* ws = (char*)d_ws;
  unsigned short* wqkvT = (unsigned short*)(ws);              // 3072x1024 bf16
  unsigned short* woT   = (unsigned short*)(ws + 6291456);    // 1024x1024
  unsigned short* w1T   = (unsigned short*)(ws + 8388608);    // 4096x1024
  unsigned short* w2T   = (unsigned short*)(ws + 16777216);   // 1024x4096
  unsigned short* h_bf  = (unsigned short*)(ws + 25165824);   // 4096x1024 (reused as h2)
  unsigned short* qkv   = (unsigned short*)(ws + 33554432);   // 4096x3072
  unsigned short* aout  = (unsigned short*)(ws + 58720256);   // 4096x1024
  unsigned int*   mbits = (unsigned int*)(ws + 67108864);     // 2048x64 words (512 KB)
  int*            cols  = (int*)(ws + 67633152);              // 32x2048 ints (256 KB)
  int*            ncols = (int*)(ws + 67895296);              // 32 ints
  unsigned int*   rmask = (unsigned int*)(ws + 67895424);     // 32x64x64 words (512 KB)
  unsigned short* ff1   = qkv;                                // reuse: 4096x4096

  packmask<<<512,256,0,stream>>>(mask, mbits);
  build_cols<<<32,64,0,stream>>>(mbits, cols, ncols);
  build_rmask<<<32,256,0,stream>>>(mbits, cols, ncols, rmask);
  transcvt<<<dim3(32,32),256,0,stream>>>(Wq, wqkvT,               1024, 1024);
  transcvt<<<dim3(32,32),256,0,stream>>>(Wk, wqkvT + 1024*1024,   1024, 1024);
  transcvt<<<dim3(32,32),256,0,stream>>>(Wv, wqkvT + 2*1024*1024, 1024, 1024);
  transcvt<<<dim3(32,32),256,0,stream>>>(Wo, woT,                 1024, 1024);
  transcvt<<<dim3(128,32),256,0,stream>>>(W1, w1T, 1024, 4096);
  transcvt<<<dim3(32,128),256,0,stream>>>(W2, w2T, 4096, 1024);

  ln_kernel<<<4096,256,0,stream>>>(x, ln1_g, ln1_b, h_bf);
  gemm_bt<false,false,false,true><<<dim3(32,24),256,0,stream>>>(h_bf, wqkvT, qkv, nullptr, nullptr, 4096, 3072, 1024);
  attn_kernel<<<dim3(32,32),256,0,stream>>>(qkv, cols, ncols, rmask, aout);
  attn_lastrow<<<dim3(2,16),256,0,stream>>>(qkv, aout);
  gemm_bt_n64<true,true,false><<<dim3(32,16),256,0,stream>>>(aout, woT, out, bo, x, 4096, 1024, 1024);
  ln_kernel<<<4096,256,0,stream>>>(out, ln2_g, ln2_b, h_bf);
  gemm_bt<true,true,false,true><<<dim3(32,32),256,0,stream>>>(h_bf, w1T, ff1, b1, nullptr, 4096, 4096, 1024);
  gemm_bt_n64<true,true,false><<<dim3(32,16),256,0,stream>>>(ff1, w2T, out, b2, out, 4096, 1024, 4096);
}

// Round 7
// 431.416 us; speedup vs baseline: 1.3364x; 1.0545x over previous
//
#include <hip/hip_runtime.h>

#define T_SEQ 2048

typedef __attribute__((ext_vector_type(8))) short short8;
typedef __attribute__((ext_vector_type(4))) float f32x4;

__device__ __forceinline__ unsigned short f32_to_bf16(float f){
  unsigned int u = __float_as_uint(f);
  u += 0x7fffu + ((u>>16)&1u);
  return (unsigned short)(u>>16);
}
__device__ __forceinline__ float bf16_to_f32(unsigned short h){
  unsigned int u = ((unsigned int)h) << 16;
  return __uint_as_float(u);
}

// async global->LDS, 16B per lane. LDS dest = wave-uniform base + lane*16.
__device__ __forceinline__ void g2l16(const void* g, void* l){
  __builtin_amdgcn_global_load_lds(
      (const __attribute__((address_space(1))) void*)g,
      (__attribute__((address_space(3))) void*)l, 16, 0, 0);
}

// call-free exact-GELU: Abramowitz-Stegun 7.1.26 erf, |eps|<=1.5e-7
__device__ __forceinline__ float gelu_exact(float v){
  float s = v * 0.70710678118f;
  float a = fabsf(s);
  float t = __builtin_amdgcn_rcpf(1.f + 0.3275911f*a);
  float p = t*(0.254829592f + t*(-0.284496736f + t*(1.421413741f +
            t*(-1.453152027f + t*1.061405429f))));
  float erf_a = 1.f - p*__expf(-a*a);
  float erf_s = (s < 0.f) ? -erf_a : erf_a;
  return 0.5f*v*(1.f + erf_s);
}

// ---------------------------------------------------------------- mask pack
__global__ __launch_bounds__(256) void packmask(const unsigned char* __restrict__ mraw,
                                                unsigned int* __restrict__ mbits){
  bool is_byte = (mraw[2049] == 1);
  int w = blockIdx.x*256 + threadIdx.x;          // word index, T*64 total
  int row = w >> 6, wc = w & 63;
  unsigned int bits = 0u;
  if (is_byte){
    const unsigned char* p = mraw + (size_t)row*T_SEQ + wc*32;
    #pragma unroll
    for (int j=0;j<32;j++) bits |= (p[j] ? 1u : 0u) << j;
  } else {
    const int* p = (const int*)mraw + (size_t)row*T_SEQ + wc*32;
    #pragma unroll
    for (int j=0;j<32;j++) bits |= (p[j] != 0 ? 1u : 0u) << j;
  }
  mbits[w] = bits;
}

// ------------------------------------------- BigBird column-list precompute
__global__ __launch_bounds__(64) void build_cols(const unsigned int* __restrict__ mbits,
                                                 int* __restrict__ cols,
                                                 int* __restrict__ ncols){
  int qt = blockIdx.x, lane = threadIdx.x;       // 64 lanes, one word each
  unsigned int w = 0;
  for (int r=0;r<64;r++){
    int row = qt*64 + r;
    if (row == T_SEQ-1) continue;                // dense last row excluded
    w |= mbits[(size_t)row*64 + lane];
  }
  int pc = __popc(w);
  int inc = pc;
  #pragma unroll
  for (int d=1; d<64; d<<=1){ int t = __shfl_up(inc, d, 64); if (lane>=d) inc += t; }
  int total = __shfl(inc, 63, 64);
  int idx = inc - pc;                            // exclusive prefix
  unsigned int ww = w;
  while (ww){ int b = __ffs(ww)-1; ww &= ww-1; cols[qt*2048 + idx++] = lane*32 + b; }
  for (int j = total + lane; j < 2048; j += 64) cols[qt*2048 + j] = -1;
  if (lane==0) ncols[qt] = (total + 63) & ~63;
}

// Remap mask bits onto gathered-column index space: rmask[qt][row][word].
__global__ __launch_bounds__(256) void build_rmask(const unsigned int* __restrict__ mbits,
                                                   const int* __restrict__ cols,
                                                   const int* __restrict__ ncols,
                                                   unsigned int* __restrict__ rmask){
  int qt = blockIdx.x, tid = threadIdx.x;
  int nw = ncols[qt] >> 5;                       // words actually used
  for (int e = tid; e < 64*nw; e += 256){
    int row = e / nw, wj = e % nw;
    const unsigned int* mrow = mbits + (size_t)(qt*64+row)*64;
    unsigned int bits = 0;
    #pragma unroll
    for (int b=0;b<32;b++){
      int j = wj*32 + b;
      int c = cols[qt*2048 + j];
      if (c >= 0) bits |= ((mrow[c>>5] >> (c&31)) & 1u) << b;
    }
    rmask[(size_t)(qt*64+row)*64 + wj] = bits;
  }
}

// ------------------------------------------------- weight transpose+convert
__global__ __launch_bounds__(256) void transcvt(const float* __restrict__ W,
                                                unsigned short* __restrict__ WT,
                                                int K, int N){
  __shared__ float tile[32][33];
  int tx = threadIdx.x & 31, ty = threadIdx.x >> 5;
  int n0 = blockIdx.x*32, k0 = blockIdx.y*32;
  #pragma unroll
  for (int j=0;j<32;j+=8)
    tile[ty+j][tx] = W[(size_t)(k0+ty+j)*N + n0 + tx];
  __syncthreads();
  #pragma unroll
  for (int j=0;j<32;j+=8)
    WT[(size_t)(n0+ty+j)*K + k0 + tx] = f32_to_bf16(tile[tx][ty+j]);
}

// ---------------------------------------------------------------- layernorm
__global__ __launch_bounds__(256) void ln_kernel(const float* __restrict__ x,
                                                 const float* __restrict__ g,
                                                 const float* __restrict__ b,
                                                 unsigned short* __restrict__ out){
  int row = blockIdx.x, tid = threadIdx.x;
  const float* xr = x + (size_t)row*1024;
  float4 xv = *(const float4*)(xr + tid*4);
  float s  = xv.x+xv.y+xv.z+xv.w;
  float s2 = xv.x*xv.x + xv.y*xv.y + xv.z*xv.z + xv.w*xv.w;
  #pragma unroll
  for (int d=1; d<64; d<<=1){ s += __shfl_xor(s,d,64); s2 += __shfl_xor(s2,d,64); }
  __shared__ float ls[4], ls2[4];
  int wid = tid >> 6;
  if ((tid & 63) == 0){ ls[wid]=s; ls2[wid]=s2; }
  __syncthreads();
  float tot = ls[0]+ls[1]+ls[2]+ls[3];
  float tot2= ls2[0]+ls2[1]+ls2[2]+ls2[3];
  float mu  = tot * (1.f/1024.f);
  float var = tot2 * (1.f/1024.f) - mu*mu;
  float inv = rsqrtf(var + 1e-5f);
  float4 gv = *(const float4*)(g + tid*4);
  float4 bv = *(const float4*)(b + tid*4);
  unsigned short o0 = f32_to_bf16((xv.x-mu)*inv*gv.x + bv.x);
  unsigned short o1 = f32_to_bf16((xv.y-mu)*inv*gv.y + bv.y);
  unsigned short o2 = f32_to_bf16((xv.z-mu)*inv*gv.z + bv.z);
  unsigned short o3 = f32_to_bf16((xv.w-mu)*inv*gv.w + bv.w);
  unsigned short* op = out + (size_t)row*1024 + tid*4;
  op[0]=o0; op[1]=o1; op[2]=o2; op[3]=o3;
}

// ------------------------------------------------------------------- GEMM
// 128x128 tile, BK=32. XOR chunk swizzle: LDS slot chunk c of row r holds
// global chunk c ^ ((r>>1)&3) -> ds_read_b128 spans all 8 bank-quads (2-way).
template<bool GELU, bool BIAS, bool RES, bool OUTBF>
__global__ __launch_bounds__(256,2) void gemm_bt(const unsigned short* __restrict__ A,
                                                 const unsigned short* __restrict__ BT,
                                                 void* __restrict__ Cout,
                                                 const float* __restrict__ bias,
                                                 const float* __restrict__ res,
                                                 int M, int N, int K){
  __shared__ unsigned short sA[128*32];
  __shared__ unsigned short sB[128*32];
  int tid = threadIdx.x;
  int m0 = blockIdx.x*128, n0 = blockIdx.y*128;
  int wid = tid>>6, lane = tid&63;
  int wm = (wid>>1)*64, wn = (wid&1)*64;
  int l16 = lane&15, quad = lane>>4;
  int qa = (quad ^ ((l16>>1)&3))*8;   // swizzled read chunk (lane-constant)

  f32x4 acc[4][4] = {};
  for (int k0=0; k0<K; k0+=32){
    #pragma unroll
    for (int i=0;i<2;i++){
      int t = i*256 + tid;                         // [0,512)
      int row = t>>2;
      int kc = ((t&3) ^ ((row>>1)&3))*8;           // swizzled source chunk
      int wb = i*256 + (tid & ~63);                // lane0's t for this wave
      g2l16(A  + (size_t)(m0+row)*K + k0 + kc, sA + wb*8);
      g2l16(BT + (size_t)(n0+row)*K + k0 + kc, sB + wb*8);
    }
    __syncthreads();
    short8 af[4], bf[4];
    #pragma unroll
    for (int mi=0;mi<4;mi++) af[mi] = *(const short8*)(sA + (wm+mi*16+l16)*32 + qa);
    #pragma unroll
    for (int ni=0;ni<4;ni++) bf[ni] = *(const short8*)(sB + (wn+ni*16+l16)*32 + qa);
    #pragma unroll
    for (int mi=0;mi<4;mi++)
      #pragma unroll
      for (int ni=0;ni<4;ni++)
        acc[mi][ni] = __builtin_amdgcn_mfma_f32_16x16x32_bf16(af[mi], bf[ni], acc[mi][ni], 0,0,0);
    __syncthreads();
  }
  #pragma unroll
  for (int mi=0;mi<4;mi++)
    #pragma unroll
    for (int ni=0;ni<4;ni++){
      int col = n0 + wn + ni*16 + l16;
      float bval = 0.f;
      if constexpr (BIAS) bval = bias[col];
      #pragma unroll
      for (int r=0;r<4;r++){
        int row = m0 + wm + mi*16 + quad*4 + r;
        float v = acc[mi][ni][r] + bval;
        if constexpr (GELU) v = gelu_exact(v);
        if constexpr (RES)  v += res[(size_t)row*N + col];
        if constexpr (OUTBF) ((unsigned short*)Cout)[(size_t)row*N + col] = f32_to_bf16(v);
        else                 ((float*)Cout)[(size_t)row*N + col] = v;
      }
    }
}

// 128x64-tile, BK=64 variant for N=1024 outputs (512 blocks -> 2/CU).
// 3-bit XOR swizzle (rows are 64 elems = full bank span unswizzled).
template<bool BIAS, bool RES, bool OUTBF>
__global__ __launch_bounds__(256,2) void gemm_bt_n64(const unsigned short* __restrict__ A,
                                                     const unsigned short* __restrict__ BT,
                                                     void* __restrict__ Cout,
                                                     const float* __restrict__ bias,
                                                     const float* __restrict__ res,
                                                     int M, int N, int K){
  __shared__ unsigned short sA[128*64];
  __shared__ unsigned short sB[64*64];
  int tid = threadIdx.x;
  int m0 = blockIdx.x*128, n0 = blockIdx.y*64;
  int wid = tid>>6, lane = tid&63;
  int wm = (wid>>1)*64, wn = (wid&1)*32;
  int l16 = lane&15, quad = lane>>4;
  int qa0 = (quad     ^ (l16&7))*8;   // k-slice 0 read chunk
  int qa1 = ((quad+4) ^ (l16&7))*8;   // k-slice 1 read chunk

  f32x4 acc[4][2] = {};
  for (int k0=0; k0<K; k0+=64){
    #pragma unroll
    for (int i=0;i<4;i++){
      int t = i*256 + tid;                         // [0,1024)
      int row = t>>3;
      int kc = ((t&7) ^ (row&7))*8;
      int wb = i*256 + (tid & ~63);
      g2l16(A + (size_t)(m0+row)*K + k0 + kc, sA + wb*8);
    }
    #pragma unroll
    for (int i=0;i<2;i++){
      int t = i*256 + tid;                         // [0,512)
      int row = t>>3;
      int kc = ((t&7) ^ (row&7))*8;
      int wb = i*256 + (tid & ~63);
      g2l16(BT + (size_t)(n0+row)*K + k0 + kc, sB + wb*8);
    }
    __syncthreads();
    #pragma unroll
    for (int kk=0;kk<2;kk++){
      int qa = kk ? qa1 : qa0;
      short8 af[4], bf[2];
      #pragma unroll
      for (int mi=0;mi<4;mi++) af[mi] = *(const short8*)(sA + (wm+mi*16+l16)*64 + qa);
      #pragma unroll
      for (int ni=0;ni<2;ni++) bf[ni] = *(const short8*)(sB + (wn+ni*16+l16)*64 + qa);
      #pragma unroll
      for (int mi=0;mi<4;mi++)
        #pragma unroll
        for (int ni=0;ni<2;ni++)
          acc[mi][ni] = __builtin_amdgcn_mfma_f32_16x16x32_bf16(af[mi], bf[ni], acc[mi][ni], 0,0,0);
    }
    __syncthreads();
  }
  #pragma unroll
  for (int mi=0;mi<4;mi++)
    #pragma unroll
    for (int ni=0;ni<2;ni++){
      int col = n0 + wn + ni*16 + l16;
      float bval = 0.f;
      if constexpr (BIAS) bval = bias[col];
      #pragma unroll
      for (int r=0;r<4;r++){
        int row = m0 + wm + mi*16 + quad*4 + r;
        float v = acc[mi][ni][r] + bval;
        if constexpr (RES)  v += res[(size_t)row*N + col];
        if constexpr (OUTBF) ((unsigned short*)Cout)[(size_t)row*N + col] = f32_to_bf16(v);
        else                 ((float*)Cout)[(size_t)row*N + col] = v;
      }
    }
}

// ------------------------------------------------------------- attention
// Sparse-gather flash attention over compacted column tiles.
__global__ __launch_bounds__(256,4) void attn_kernel(const unsigned short* __restrict__ qkv,
                                                     const int* __restrict__ cols,
                                                     const int* __restrict__ ncols,
                                                     const unsigned int* __restrict__ rmask,
                                                     unsigned short* __restrict__ out){
  int qt = 31 - blockIdx.x;
  int bh = blockIdx.y;                // 0..31
  int b = bh >> 4, h = bh & 15;
  int tid = threadIdx.x, wid = tid>>6, lane = tid&63;
  int l16 = lane&15, quad = lane>>4;
  const int RS = 3072;
  const size_t base = (size_t)b * T_SEQ * RS;
  int q0 = qt*64;

  __shared__ unsigned short sK [64*72];    // [krow][dim] pad 72
  __shared__ unsigned short sVt[64*72];    // [dim][krow] pad 72
  __shared__ unsigned short sX [64*72];    // raw V staging
  __shared__ unsigned short sP [4][16*72]; // per-wave P tile

  const int* gcols = cols + qt*2048;
  int niter = ncols[qt] >> 6;

  int qrow = q0 + wid*16 + l16;
  const unsigned short* qptr = qkv + base + (size_t)qrow*RS + h*64;
  short8 qf0 = *(const short8*)(qptr + quad*8);
  short8 qf1 = *(const short8*)(qptr + 32 + quad*8);

  f32x4 o[4] = {};
  float m_i[4], l_i[4];
  #pragma unroll
  for (int r=0;r<4;r++){ m_i[r] = -1e30f; l_i[r] = 0.f; }

  int krow0 = tid>>3, krow1 = 32 + (tid>>3), dc = (tid&7)*8;
  int c0n = gcols[krow0], c1n = gcols[krow1];

  for (int kt=0; kt<niter; ++kt){
    int c0 = c0n < 0 ? 0 : c0n;
    int c1 = c1n < 0 ? 0 : c1n;
    const unsigned short* p0 = qkv + base + (size_t)c0*RS + 1024 + h*64 + dc;
    const unsigned short* p1 = qkv + base + (size_t)c1*RS + 1024 + h*64 + dc;
    uint4 k0 = *(const uint4*)p0;
    uint4 k1 = *(const uint4*)p1;
    uint4 v0 = *(const uint4*)(p0 + 1024);
    uint4 v1 = *(const uint4*)(p1 + 1024);
    if (kt+1 < niter){
      c0n = gcols[(kt+1)*64 + krow0];
      c1n = gcols[(kt+1)*64 + krow1];
    }
    __syncthreads();                       // prev iter's LDS readers done
    *(uint4*)(sK + krow0*72 + dc) = k0;
    *(uint4*)(sK + krow1*72 + dc) = k1;
    *(uint4*)(sX + krow0*72 + dc) = v0;
    *(uint4*)(sX + krow1*72 + dc) = v1;
    __syncthreads();                       // sK/sX visible

    // transpose sX -> sVt (krow lane-fast => conflict-free)
    #pragma unroll
    for (int pass=0; pass<2; ++pass){
      int dg = pass*4 + wid;
      unsigned short v8[8];
      *(uint4*)v8 = *(const uint4*)(sX + lane*72 + dg*8);
      #pragma unroll
      for (int j=0;j<8;j++) sVt[(dg*8+j)*72 + lane] = v8[j];
    }

    // S = Q @ K^T
    f32x4 s[4];
    #pragma unroll
    for (int nt=0;nt<4;nt++){
      f32x4 z = {};
      short8 kb0 = *(const short8*)(sK + (nt*16+l16)*72 + quad*8);
      short8 kb1 = *(const short8*)(sK + (nt*16+l16)*72 + 32 + quad*8);
      z = __builtin_amdgcn_mfma_f32_16x16x32_bf16(qf0, kb0, z, 0,0,0);
      z = __builtin_amdgcn_mfma_f32_16x16x32_bf16(qf1, kb1, z, 0,0,0);
      s[nt] = z;
    }

    // mask (remapped bits) + scale
    float rowmax[4];
    #pragma unroll
    for (int r=0;r<4;r++){
      int rowin = wid*16 + quad*4 + r;
      const unsigned int* mrow = rmask + (size_t)(qt*64+rowin)*64 + kt*2;
      unsigned long long m64 = (unsigned long long)mrow[0] |
                               ((unsigned long long)mrow[1] << 32);
      float rm = -1e30f;
      #pragma unroll
      for (int nt=0;nt<4;nt++){
        int c6 = nt*16 + l16;
        bool ok = (m64 >> c6) & 1ull;
        float v = ok ? s[nt][r]*0.125f : -1e30f;
        s[nt][r] = v;
        rm = fmaxf(rm, v);
      }
      rowmax[r] = rm;
    }
    #pragma unroll
    for (int r=0;r<4;r++){
      float v = rowmax[r];
      #pragma unroll
      for (int d=1; d<16; d<<=1) v = fmaxf(v, __shfl_xor(v,d,64));
      rowmax[r] = v;
    }
    float alpha[4];
    #pragma unroll
    for (int r=0;r<4;r++){
      float mnew = fmaxf(m_i[r], rowmax[r]);
      alpha[r] = __expf(m_i[r] - mnew);
      m_i[r] = mnew;
    }
    #pragma unroll
    for (int nt=0;nt<4;nt++)
      #pragma unroll
      for (int r=0;r<4;r++)
        s[nt][r] = __expf(s[nt][r] - m_i[r]);
    #pragma unroll
    for (int r=0;r<4;r++){
      float v = s[0][r]+s[1][r]+s[2][r]+s[3][r];
      #pragma unroll
      for (int d=1; d<16; d<<=1) v += __shfl_xor(v,d,64);
      l_i[r] = l_i[r]*alpha[r] + v;
    }
    // P: C-layout -> per-wave LDS -> A-layout (same-wave RAW, no barrier)
    #pragma unroll
    for (int nt=0;nt<4;nt++)
      #pragma unroll
      for (int r=0;r<4;r++)
        sP[wid][(quad*4+r)*72 + nt*16 + l16] = f32_to_bf16(s[nt][r]);
    short8 p0f = *(const short8*)(sP[wid] + l16*72 + quad*8);
    short8 p1f = *(const short8*)(sP[wid] + l16*72 + 32 + quad*8);
    #pragma unroll
    for (int nt=0;nt<4;nt++)
      #pragma unroll
      for (int r=0;r<4;r++)
        o[nt][r] *= alpha[r];
    __syncthreads();                       // sVt complete
    #pragma unroll
    for (int nt=0;nt<4;nt++){
      short8 vb0 = *(const short8*)(sVt + (nt*16+l16)*72 + quad*8);
      short8 vb1 = *(const short8*)(sVt + (nt*16+l16)*72 + 32 + quad*8);
      o[nt] = __builtin_amdgcn_mfma_f32_16x16x32_bf16(p0f, vb0, o[nt], 0,0,0);
      o[nt] = __builtin_amdgcn_mfma_f32_16x16x32_bf16(p1f, vb1, o[nt], 0,0,0);
    }
  }
  #pragma unroll
  for (int nt=0;nt<4;nt++)
    #pragma unroll
    for (int r=0;r<4;r++){
      int row = q0 + wid*16 + quad*4 + r;
      int col = h*64 + nt*16 + l16;
      out[(size_t)(b*T_SEQ + row)*1024 + col] = f32_to_bf16(o[nt][r] / l_i[r]);
    }
}

// ---------------------------------------------------- dense last-row attn
__global__ __launch_bounds__(256,1) void attn_lastrow(const unsigned short* __restrict__ qkv,
                                                      unsigned short* __restrict__ out){
  int b = blockIdx.x, h = blockIdx.y;
  int tid = threadIdx.x, lane = tid & 63, wid = tid >> 6;
  const int RS = 3072;
  const size_t base = (size_t)b * T_SEQ * RS;

  __shared__ float sS[2048];
  __shared__ float sRed[4];
  __shared__ float sO[4][64];
  __shared__ unsigned short sQ[64];

  if (tid < 8)
    *(uint4*)(sQ + tid*8) = *(const uint4*)(qkv + base + (size_t)(T_SEQ-1)*RS + h*64 + tid*8);
  __syncthreads();
  float qf[64];
  #pragma unroll
  for (int j=0;j<64;j++) qf[j] = bf16_to_f32(sQ[j]);

  float lmax = -1e30f;
  for (int k = tid; k < T_SEQ; k += 256){
    const unsigned short* kp = qkv + base + (size_t)k*RS + 1024 + h*64;
    float acc = 0.f;
    #pragma unroll
    for (int c=0;c<8;c++){
      unsigned short kk[8];
      *(uint4*)kk = *(const uint4*)(kp + c*8);
      #pragma unroll
      for (int j=0;j<8;j++) acc += qf[c*8+j]*bf16_to_f32(kk[j]);
    }
    float sv = acc * 0.125f;
    sS[k] = sv;
    lmax = fmaxf(lmax, sv);
  }
  #pragma unroll
  for (int d=1; d<64; d<<=1) lmax = fmaxf(lmax, __shfl_xor(lmax, d, 64));
  if (lane == 0) sRed[wid] = lmax;
  __syncthreads();
  float m = fmaxf(fmaxf(sRed[0],sRed[1]), fmaxf(sRed[2],sRed[3]));
  float lsum = 0.f;
  for (int k = tid; k < T_SEQ; k += 256){
    float p = __expf(sS[k] - m);
    sS[k] = p;
    lsum += p;
  }
  #pragma unroll
  for (int d=1; d<64; d<<=1) lsum += __shfl_xor(lsum, d, 64);
  __syncthreads();
  if (lane == 0) sRed[wid] = lsum;
  __syncthreads();
  float l = sRed[0]+sRed[1]+sRed[2]+sRed[3];

  int d = tid & 63;
  int chunk = wid;
  float oacc = 0.f;
  const unsigned short* vp = qkv + base + 2048 + h*64 + d;
  #pragma unroll 4
  for (int k = chunk*512; k < chunk*512 + 512; ++k)
    oacc += sS[k] * bf16_to_f32(vp[(size_t)k*RS]);
  sO[chunk][d] = oacc;
  __syncthreads();
  if (wid == 0){
    float ov = (sO[0][d]+sO[1][d]+sO[2][d]+sO[3][d]) / l;
    out[(size_t)(b*T_SEQ + T_SEQ-1)*1024 + h*64 + d] = f32_to_bf16(ov);
  }
}

// ---------------------------------------------------------------- launch
extern "C" void kernel_launch(void* const* d_in, const int* in_sizes, int n_in,
                              void* d_out, int out_size, void* d_ws, size_t ws_size,
                              hipStream_t stream) {
  const float* x     = (const float*)d_in[0];
  const unsigned char* mask = (const unsigned char*)d_in[1];
  const float* ln1_g = (const float*)d_in[2];
  const float* ln1_b = (const float*)d_in[3];
  const float* ln2_g = (const float*)d_in[4];
  const float* ln2_b = (const float*)d_in[5];
  const float* Wq = (const float*)d_in[6];
  const float* Wk = (const float*)d_in[7];
  const float* Wv = (const float*)d_in[8];
  const float* Wo = (const float*)d_in[9];
  const float* bo = (const float*)d_in[10];
  const float* W1 = (const float*)d_in[11];
  const float* b1 = (const float*)d_in[12];
  const float* W2 = (const float*)d_in[13];
  const float* b2 = (const float*)d_in[14];
  float* out = (float*)d_out;

  char* ws = (char*)d_ws;
  unsigned short* wqkvT = (unsigned short*)(ws);              // 3072x1024 bf16
  unsigned short* woT   = (unsigned short*)(ws + 6291456);    // 1024x1024
  unsigned short* w1T   = (unsigned short*)(ws + 8388608);    // 4096x1024
  unsigned short* w2T   = (unsigned short*)(ws + 16777216);   // 1024x4096
  unsigned short* h_bf  = (unsigned short*)(ws + 25165824);   // 4096x1024 (reused as h2)
  unsigned short* qkv   = (unsigned short*)(ws + 33554432);   // 4096x3072
  unsigned short* aout  = (unsigned short*)(ws + 58720256);   // 4096x1024
  unsigned int*   mbits = (unsigned int*)(ws + 67108864);     // 2048x64 words (512 KB)
  int*            cols  = (int*)(ws + 67633152);              // 32x2048 ints (256 KB)
  int*            ncols = (int*)(ws + 67895296);              // 32 ints
  unsigned int*   rmask = (unsigned int*)(ws + 67895424);     // 32x64x64 words (512 KB)
  unsigned short* ff1   = qkv;                                // reuse: 4096x4096

  packmask<<<512,256,0,stream>>>(mask, mbits);
  build_cols<<<32,64,0,stream>>>(mbits, cols, ncols);
  build_rmask<<<32,256,0,stream>>>(mbits, cols, ncols, rmask);
  transcvt<<<dim3(32,32),256,0,stream>>>(Wq, wqkvT,               1024, 1024);
  transcvt<<<dim3(32,32),256,0,stream>>>(Wk, wqkvT + 1024*1024,   1024, 1024);
  transcvt<<<dim3(32,32),256,0,stream>>>(Wv, wqkvT + 2*1024*1024, 1024, 1024);
  transcvt<<<dim3(32,32),256,0,stream>>>(Wo, woT,                 1024, 1024);
  transcvt<<<dim3(128,32),256,0,stream>>>(W1, w1T, 1024, 4096);
  transcvt<<<dim3(32,128),256,0,stream>>>(W2, w2T, 4096, 1024);

  ln_kernel<<<4096,256,0,stream>>>(x, ln1_g, ln1_b, h_bf);
  gemm_bt<false,false,false,true><<<dim3(32,24),256,0,stream>>>(h_bf, wqkvT, qkv, nullptr, nullptr, 4096, 3072, 1024);
  attn_kernel<<<dim3(32,32),256,0,stream>>>(qkv, cols, ncols, rmask, aout);
  attn_lastrow<<<dim3(2,16),256,0,stream>>>(qkv, aout);
  gemm_bt_n64<true,true,false><<<dim3(32,16),256,0,stream>>>(aout, woT, out, bo, x, 4096, 1024, 1024);
  ln_kernel<<<4096,256,0,stream>>>(out, ln2_g, ln2_b, h_bf);
  gemm_bt<true,true,false,true><<<dim3(32,32),256,0,stream>>>(h_bf, w1T, ff1, b1, nullptr, 4096, 4096, 1024);
  gemm_bt_n64<true,true,false><<<dim3(32,16),256,0,stream>>>(ff1, w2T, out, b2, out, 4096, 1024, 4096);
}

// Round 8
// 370.973 us; speedup vs baseline: 1.5541x; 1.1629x over previous
//
#include <hip/hip_runtime.h>

#define T_SEQ 2048

typedef __attribute__((ext_vector_type(8))) short short8;
typedef __attribute__((ext_vector_type(4))) float f32x4;

__device__ __forceinline__ unsigned short f32_to_bf16(float f){
  unsigned int u = __float_as_uint(f);
  u += 0x7fffu + ((u>>16)&1u);
  return (unsigned short)(u>>16);
}
__device__ __forceinline__ float bf16_to_f32(unsigned short h){
  unsigned int u = ((unsigned int)h) << 16;
  return __uint_as_float(u);
}

// async global->LDS, 16B per lane. LDS dest = wave-uniform base + lane*16.
__device__ __forceinline__ void g2l16(const void* g, void* l){
  __builtin_amdgcn_global_load_lds(
      (const __attribute__((address_space(1))) void*)g,
      (__attribute__((address_space(3))) void*)l, 16, 0, 0);
}

// call-free exact-GELU: Abramowitz-Stegun 7.1.26 erf, |eps|<=1.5e-7
__device__ __forceinline__ float gelu_exact(float v){
  float s = v * 0.70710678118f;
  float a = fabsf(s);
  float t = __builtin_amdgcn_rcpf(1.f + 0.3275911f*a);
  float p = t*(0.254829592f + t*(-0.284496736f + t*(1.421413741f +
            t*(-1.453152027f + t*1.061405429f))));
  float erf_a = 1.f - p*__expf(-a*a);
  float erf_s = (s < 0.f) ? -erf_a : erf_a;
  return 0.5f*v*(1.f + erf_s);
}

// ---------------------------------------------------------------- mask pack
__global__ __launch_bounds__(256) void packmask(const unsigned char* __restrict__ mraw,
                                                unsigned int* __restrict__ mbits){
  bool is_byte = (mraw[2049] == 1);
  int w = blockIdx.x*256 + threadIdx.x;          // word index, T*64 total
  int row = w >> 6, wc = w & 63;
  unsigned int bits = 0u;
  if (is_byte){
    const unsigned char* p = mraw + (size_t)row*T_SEQ + wc*32;
    #pragma unroll
    for (int j=0;j<32;j++) bits |= (p[j] ? 1u : 0u) << j;
  } else {
    const int* p = (const int*)mraw + (size_t)row*T_SEQ + wc*32;
    #pragma unroll
    for (int j=0;j<32;j++) bits |= (p[j] != 0 ? 1u : 0u) << j;
  }
  mbits[w] = bits;
}

// ------------------------------------------- BigBird column-list precompute
__global__ __launch_bounds__(64) void build_cols(const unsigned int* __restrict__ mbits,
                                                 int* __restrict__ cols,
                                                 int* __restrict__ ncols){
  int qt = blockIdx.x, lane = threadIdx.x;       // 64 lanes, one word each
  unsigned int w = 0;
  for (int r=0;r<64;r++){
    int row = qt*64 + r;
    if (row == T_SEQ-1) continue;                // dense last row excluded
    w |= mbits[(size_t)row*64 + lane];
  }
  int pc = __popc(w);
  int inc = pc;
  #pragma unroll
  for (int d=1; d<64; d<<=1){ int t = __shfl_up(inc, d, 64); if (lane>=d) inc += t; }
  int total = __shfl(inc, 63, 64);
  int idx = inc - pc;                            // exclusive prefix
  unsigned int ww = w;
  while (ww){ int b = __ffs(ww)-1; ww &= ww-1; cols[qt*2048 + idx++] = lane*32 + b; }
  for (int j = total + lane; j < 2048; j += 64) cols[qt*2048 + j] = -1;
  if (lane==0) ncols[qt] = (total + 63) & ~63;
}

// Remap mask bits onto gathered-column index space: rmask[qt][row][word].
__global__ __launch_bounds__(256) void build_rmask(const unsigned int* __restrict__ mbits,
                                                   const int* __restrict__ cols,
                                                   const int* __restrict__ ncols,
                                                   unsigned int* __restrict__ rmask){
  int qt = blockIdx.x, tid = threadIdx.x;
  int nw = ncols[qt] >> 5;                       // words actually used
  for (int e = tid; e < 64*nw; e += 256){
    int row = e / nw, wj = e % nw;
    const unsigned int* mrow = mbits + (size_t)(qt*64+row)*64;
    unsigned int bits = 0;
    #pragma unroll
    for (int b=0;b<32;b++){
      int j = wj*32 + b;
      int c = cols[qt*2048 + j];
      if (c >= 0) bits |= ((mrow[c>>5] >> (c&31)) & 1u) << b;
    }
    rmask[(size_t)(qt*64+row)*64 + wj] = bits;
  }
}

// ------------------------------------------------- weight transpose+convert
__global__ __launch_bounds__(256) void transcvt(const float* __restrict__ W,
                                                unsigned short* __restrict__ WT,
                                                int K, int N){
  __shared__ float tile[32][33];
  int tx = threadIdx.x & 31, ty = threadIdx.x >> 5;
  int n0 = blockIdx.x*32, k0 = blockIdx.y*32;
  #pragma unroll
  for (int j=0;j<32;j+=8)
    tile[ty+j][tx] = W[(size_t)(k0+ty+j)*N + n0 + tx];
  __syncthreads();
  #pragma unroll
  for (int j=0;j<32;j+=8)
    WT[(size_t)(n0+ty+j)*K + k0 + tx] = f32_to_bf16(tile[tx][ty+j]);
}

// ---------------------------------------------------------------- layernorm
__global__ __launch_bounds__(256) void ln_kernel(const float* __restrict__ x,
                                                 const float* __restrict__ g,
                                                 const float* __restrict__ b,
                                                 unsigned short* __restrict__ out){
  int row = blockIdx.x, tid = threadIdx.x;
  const float* xr = x + (size_t)row*1024;
  float4 xv = *(const float4*)(xr + tid*4);
  float s  = xv.x+xv.y+xv.z+xv.w;
  float s2 = xv.x*xv.x + xv.y*xv.y + xv.z*xv.z + xv.w*xv.w;
  #pragma unroll
  for (int d=1; d<64; d<<=1){ s += __shfl_xor(s,d,64); s2 += __shfl_xor(s2,d,64); }
  __shared__ float ls[4], ls2[4];
  int wid = tid >> 6;
  if ((tid & 63) == 0){ ls[wid]=s; ls2[wid]=s2; }
  __syncthreads();
  float tot = ls[0]+ls[1]+ls[2]+ls[3];
  float tot2= ls2[0]+ls2[1]+ls2[2]+ls2[3];
  float mu  = tot * (1.f/1024.f);
  float var = tot2 * (1.f/1024.f) - mu*mu;
  float inv = rsqrtf(var + 1e-5f);
  float4 gv = *(const float4*)(g + tid*4);
  float4 bv = *(const float4*)(b + tid*4);
  unsigned short o0 = f32_to_bf16((xv.x-mu)*inv*gv.x + bv.x);
  unsigned short o1 = f32_to_bf16((xv.y-mu)*inv*gv.y + bv.y);
  unsigned short o2 = f32_to_bf16((xv.z-mu)*inv*gv.z + bv.z);
  unsigned short o3 = f32_to_bf16((xv.w-mu)*inv*gv.w + bv.w);
  unsigned short* op = out + (size_t)row*1024 + tid*4;
  op[0]=o0; op[1]=o1; op[2]=o2; op[3]=o3;
}

// ------------------------------------------------------------------- GEMM
// 128x128 tile, BK=64 (half the barrier drains of BK=32). 3-bit XOR chunk
// swizzle: LDS slot chunk c of row r holds global chunk c ^ (r&7).
template<bool GELU, bool BIAS, bool RES, bool OUTBF>
__global__ __launch_bounds__(256,4) void gemm_bt(const unsigned short* __restrict__ A,
                                                 const unsigned short* __restrict__ BT,
                                                 void* __restrict__ Cout,
                                                 const float* __restrict__ bias,
                                                 const float* __restrict__ res,
                                                 int M, int N, int K){
  __shared__ unsigned short sA[128*64];
  __shared__ unsigned short sB[128*64];
  int tid = threadIdx.x;
  int m0 = blockIdx.x*128, n0 = blockIdx.y*128;
  int wid = tid>>6, lane = tid&63;
  int wm = (wid>>1)*64, wn = (wid&1)*64;
  int l16 = lane&15, quad = lane>>4;
  int qa0 = (quad     ^ (l16&7))*8;
  int qa1 = ((quad+4) ^ (l16&7))*8;

  f32x4 acc[4][4] = {};
  for (int k0=0; k0<K; k0+=64){
    #pragma unroll
    for (int i=0;i<4;i++){
      int t = i*256 + tid;                         // [0,1024)
      int row = t>>3;
      int kc = ((t&7) ^ (row&7))*8;
      int wb = i*256 + (tid & ~63);
      g2l16(A  + (size_t)(m0+row)*K + k0 + kc, sA + wb*8);
      g2l16(BT + (size_t)(n0+row)*K + k0 + kc, sB + wb*8);
    }
    __syncthreads();
    #pragma unroll
    for (int kk=0;kk<2;kk++){
      int qa = kk ? qa1 : qa0;
      short8 af[4], bf[4];
      #pragma unroll
      for (int mi=0;mi<4;mi++) af[mi] = *(const short8*)(sA + (wm+mi*16+l16)*64 + qa);
      #pragma unroll
      for (int ni=0;ni<4;ni++) bf[ni] = *(const short8*)(sB + (wn+ni*16+l16)*64 + qa);
      #pragma unroll
      for (int mi=0;mi<4;mi++)
        #pragma unroll
        for (int ni=0;ni<4;ni++)
          acc[mi][ni] = __builtin_amdgcn_mfma_f32_16x16x32_bf16(af[mi], bf[ni], acc[mi][ni], 0,0,0);
    }
    __syncthreads();
  }
  #pragma unroll
  for (int mi=0;mi<4;mi++)
    #pragma unroll
    for (int ni=0;ni<4;ni++){
      int col = n0 + wn + ni*16 + l16;
      float bval = 0.f;
      if constexpr (BIAS) bval = bias[col];
      #pragma unroll
      for (int r=0;r<4;r++){
        int row = m0 + wm + mi*16 + quad*4 + r;
        float v = acc[mi][ni][r] + bval;
        if constexpr (GELU) v = gelu_exact(v);
        if constexpr (RES)  v += res[(size_t)row*N + col];
        if constexpr (OUTBF) ((unsigned short*)Cout)[(size_t)row*N + col] = f32_to_bf16(v);
        else                 ((float*)Cout)[(size_t)row*N + col] = v;
      }
    }
}

// 128x64-tile, BK=64 variant for N=1024 outputs (512 blocks -> 2/CU).
template<bool BIAS, bool RES, bool OUTBF>
__global__ __launch_bounds__(256,2) void gemm_bt_n64(const unsigned short* __restrict__ A,
                                                     const unsigned short* __restrict__ BT,
                                                     void* __restrict__ Cout,
                                                     const float* __restrict__ bias,
                                                     const float* __restrict__ res,
                                                     int M, int N, int K){
  __shared__ unsigned short sA[128*64];
  __shared__ unsigned short sB[64*64];
  int tid = threadIdx.x;
  int m0 = blockIdx.x*128, n0 = blockIdx.y*64;
  int wid = tid>>6, lane = tid&63;
  int wm = (wid>>1)*64, wn = (wid&1)*32;
  int l16 = lane&15, quad = lane>>4;
  int qa0 = (quad     ^ (l16&7))*8;   // k-slice 0 read chunk
  int qa1 = ((quad+4) ^ (l16&7))*8;   // k-slice 1 read chunk

  f32x4 acc[4][2] = {};
  for (int k0=0; k0<K; k0+=64){
    #pragma unroll
    for (int i=0;i<4;i++){
      int t = i*256 + tid;                         // [0,1024)
      int row = t>>3;
      int kc = ((t&7) ^ (row&7))*8;
      int wb = i*256 + (tid & ~63);
      g2l16(A + (size_t)(m0+row)*K + k0 + kc, sA + wb*8);
    }
    #pragma unroll
    for (int i=0;i<2;i++){
      int t = i*256 + tid;                         // [0,512)
      int row = t>>3;
      int kc = ((t&7) ^ (row&7))*8;
      int wb = i*256 + (tid & ~63);
      g2l16(BT + (size_t)(n0+row)*K + k0 + kc, sB + wb*8);
    }
    __syncthreads();
    #pragma unroll
    for (int kk=0;kk<2;kk++){
      int qa = kk ? qa1 : qa0;
      short8 af[4], bf[2];
      #pragma unroll
      for (int mi=0;mi<4;mi++) af[mi] = *(const short8*)(sA + (wm+mi*16+l16)*64 + qa);
      #pragma unroll
      for (int ni=0;ni<2;ni++) bf[ni] = *(const short8*)(sB + (wn+ni*16+l16)*64 + qa);
      #pragma unroll
      for (int mi=0;mi<4;mi++)
        #pragma unroll
        for (int ni=0;ni<2;ni++)
          acc[mi][ni] = __builtin_amdgcn_mfma_f32_16x16x32_bf16(af[mi], bf[ni], acc[mi][ni], 0,0,0);
    }
    __syncthreads();
  }
  #pragma unroll
  for (int mi=0;mi<4;mi++)
    #pragma unroll
    for (int ni=0;ni<2;ni++){
      int col = n0 + wn + ni*16 + l16;
      float bval = 0.f;
      if constexpr (BIAS) bval = bias[col];
      #pragma unroll
      for (int r=0;r<4;r++){
        int row = m0 + wm + mi*16 + quad*4 + r;
        float v = acc[mi][ni][r] + bval;
        if constexpr (RES)  v += res[(size_t)row*N + col];
        if constexpr (OUTBF) ((unsigned short*)Cout)[(size_t)row*N + col] = f32_to_bf16(v);
        else                 ((float*)Cout)[(size_t)row*N + col] = v;
      }
    }
}

// ------------------------------------------------------------- attention
// grid (33, 32): x<32 -> sparse-gather flash attention for q-tile 31-x;
// x==32 -> dense last-row (row T-1) attention, vectorized two-pass softmax.
// Sparse qt=31 block skips its row-2047 store (lastrow block owns it).
__global__ __launch_bounds__(256,4) void attn_kernel(const unsigned short* __restrict__ qkv,
                                                     const int* __restrict__ cols,
                                                     const int* __restrict__ ncols,
                                                     const unsigned int* __restrict__ rmask,
                                                     unsigned short* __restrict__ out){
  __shared__ __align__(16) char smem[36864];
  int bh = blockIdx.y;                // 0..31
  int b = bh >> 4, h = bh & 15;
  int tid = threadIdx.x, wid = tid>>6, lane = tid&63;
  const int RS = 3072;
  const size_t base = (size_t)b * T_SEQ * RS;

  if (blockIdx.x == 32){
    // ---------------- dense last row ----------------
    float* sS  = (float*)smem;                      // 2048 f32
    float* sOr = (float*)(smem + 8192);             // 32 x 65 f32 (padded)
    float* sRed= (float*)(smem + 16512);            // 8 f32
    unsigned short* sQ = (unsigned short*)(smem + 16544); // 64 bf16

    if (tid < 8)
      ((uint4*)sQ)[tid] = *(const uint4*)(qkv + base + (size_t)(T_SEQ-1)*RS + h*64 + tid*8);
    __syncthreads();
    unsigned short q16[64];
    #pragma unroll
    for (int c=0;c<8;c++) *(uint4*)(q16 + c*8) = ((const uint4*)sQ)[c];

    // pass 1: scores + block max
    float lmax = -1e30f;
    #pragma unroll
    for (int i=0;i<8;i++){
      int k = tid + 256*i;
      const unsigned short* kp = qkv + base + (size_t)k*RS + 1024 + h*64;
      float acc = 0.f;
      #pragma unroll
      for (int c=0;c<8;c++){
        unsigned short kk[8];
        *(uint4*)kk = *(const uint4*)(kp + c*8);
        #pragma unroll
        for (int j=0;j<8;j++) acc += bf16_to_f32(q16[c*8+j])*bf16_to_f32(kk[j]);
      }
      float sv = acc * 0.125f;
      sS[k] = sv;
      lmax = fmaxf(lmax, sv);
    }
    #pragma unroll
    for (int d=1; d<64; d<<=1) lmax = fmaxf(lmax, __shfl_xor(lmax, d, 64));
    if (lane == 0) sRed[wid] = lmax;
    __syncthreads();
    float m = fmaxf(fmaxf(sRed[0],sRed[1]), fmaxf(sRed[2],sRed[3]));
    float lsum = 0.f;
    #pragma unroll
    for (int i=0;i<8;i++){
      int k = tid + 256*i;
      float p = __expf(sS[k] - m);
      sS[k] = p;
      lsum += p;
    }
    #pragma unroll
    for (int d=1; d<64; d<<=1) lsum += __shfl_xor(lsum, d, 64);
    if (lane == 0) sRed[4+wid] = lsum;
    __syncthreads();                                // also publishes exp'd sS
    float l = sRed[4]+sRed[5]+sRed[6]+sRed[7];

    // pass 2: o[d] = sum_k p[k]*V[k][d]; 32 k-lanes x 8 d-groups
    int dg = tid & 7, kl = tid >> 3;
    float o8[8] = {};
    const unsigned short* vbase = qkv + base + 2048 + h*64 + dg*8;
    #pragma unroll 4
    for (int i=0;i<64;i++){
      int k = kl + 32*i;
      float p = sS[k];
      unsigned short vv[8];
      *(uint4*)vv = *(const uint4*)(vbase + (size_t)k*RS);
      #pragma unroll
      for (int j=0;j<8;j++) o8[j] += p * bf16_to_f32(vv[j]);
    }
    #pragma unroll
    for (int j=0;j<8;j++) sOr[kl*65 + dg*8 + j] = o8[j];
    __syncthreads();
    if (tid < 64){
      float s = 0.f;
      #pragma unroll
      for (int k2=0;k2<32;k2++) s += sOr[k2*65 + tid];
      out[(size_t)(b*T_SEQ + T_SEQ-1)*1024 + h*64 + tid] = f32_to_bf16(s / l);
    }
    return;
  }

  // ---------------- sparse q-tiles ----------------
  unsigned short* sK  = (unsigned short*)smem;            // [64][72]
  unsigned short* sVt = (unsigned short*)(smem +  9216);  // [64][72]
  unsigned short* sX  = (unsigned short*)(smem + 18432);  // [64][72]
  unsigned short* sP  = (unsigned short*)(smem + 27648);  // [4][16][72]

  int qt = 31 - blockIdx.x;
  int l16 = lane&15, quad = lane>>4;
  int q0 = qt*64;

  const int* gcols = cols + qt*2048;
  int niter = ncols[qt] >> 6;

  int qrow = q0 + wid*16 + l16;
  const unsigned short* qptr = qkv + base + (size_t)qrow*RS + h*64;
  short8 qf0 = *(const short8*)(qptr + quad*8);
  short8 qf1 = *(const short8*)(qptr + 32 + quad*8);

  f32x4 o[4] = {};
  float m_i[4], l_i[4];
  #pragma unroll
  for (int r=0;r<4;r++){ m_i[r] = -1e30f; l_i[r] = 0.f; }

  int krow0 = tid>>3, krow1 = 32 + (tid>>3), dc = (tid&7)*8;
  int c0n = gcols[krow0], c1n = gcols[krow1];

  for (int kt=0; kt<niter; ++kt){
    int c0 = c0n < 0 ? 0 : c0n;
    int c1 = c1n < 0 ? 0 : c1n;
    const unsigned short* p0 = qkv + base + (size_t)c0*RS + 1024 + h*64 + dc;
    const unsigned short* p1 = qkv + base + (size_t)c1*RS + 1024 + h*64 + dc;
    uint4 k0 = *(const uint4*)p0;
    uint4 k1 = *(const uint4*)p1;
    uint4 v0 = *(const uint4*)(p0 + 1024);
    uint4 v1 = *(const uint4*)(p1 + 1024);
    if (kt+1 < niter){
      c0n = gcols[(kt+1)*64 + krow0];
      c1n = gcols[(kt+1)*64 + krow1];
    }
    __syncthreads();                       // prev iter's LDS readers done
    *(uint4*)(sK + krow0*72 + dc) = k0;
    *(uint4*)(sK + krow1*72 + dc) = k1;
    *(uint4*)(sX + krow0*72 + dc) = v0;
    *(uint4*)(sX + krow1*72 + dc) = v1;
    __syncthreads();                       // sK/sX visible

    // transpose sX -> sVt (krow lane-fast => conflict-free)
    #pragma unroll
    for (int pass=0; pass<2; ++pass){
      int dg = pass*4 + wid;
      unsigned short v8[8];
      *(uint4*)v8 = *(const uint4*)(sX + lane*72 + dg*8);
      #pragma unroll
      for (int j=0;j<8;j++) sVt[(dg*8+j)*72 + lane] = v8[j];
    }

    // S = Q @ K^T
    f32x4 s[4];
    #pragma unroll
    for (int nt=0;nt<4;nt++){
      f32x4 z = {};
      short8 kb0 = *(const short8*)(sK + (nt*16+l16)*72 + quad*8);
      short8 kb1 = *(const short8*)(sK + (nt*16+l16)*72 + 32 + quad*8);
      z = __builtin_amdgcn_mfma_f32_16x16x32_bf16(qf0, kb0, z, 0,0,0);
      z = __builtin_amdgcn_mfma_f32_16x16x32_bf16(qf1, kb1, z, 0,0,0);
      s[nt] = z;
    }

    // mask (remapped bits) + scale
    float rowmax[4];
    #pragma unroll
    for (int r=0;r<4;r++){
      int rowin = wid*16 + quad*4 + r;
      const unsigned int* mrow = rmask + (size_t)(qt*64+rowin)*64 + kt*2;
      unsigned long long m64 = (unsigned long long)mrow[0] |
                               ((unsigned long long)mrow[1] << 32);
      float rm = -1e30f;
      #pragma unroll
      for (int nt=0;nt<4;nt++){
        int c6 = nt*16 + l16;
        bool ok = (m64 >> c6) & 1ull;
        float v = ok ? s[nt][r]*0.125f : -1e30f;
        s[nt][r] = v;
        rm = fmaxf(rm, v);
      }
      rowmax[r] = rm;
    }
    #pragma unroll
    for (int r=0;r<4;r++){
      float v = rowmax[r];
      #pragma unroll
      for (int d=1; d<16; d<<=1) v = fmaxf(v, __shfl_xor(v,d,64));
      rowmax[r] = v;
    }
    float alpha[4];
    #pragma unroll
    for (int r=0;r<4;r++){
      float mnew = fmaxf(m_i[r], rowmax[r]);
      alpha[r] = __expf(m_i[r] - mnew);
      m_i[r] = mnew;
    }
    #pragma unroll
    for (int nt=0;nt<4;nt++)
      #pragma unroll
      for (int r=0;r<4;r++)
        s[nt][r] = __expf(s[nt][r] - m_i[r]);
    #pragma unroll
    for (int r=0;r<4;r++){
      float v = s[0][r]+s[1][r]+s[2][r]+s[3][r];
      #pragma unroll
      for (int d=1; d<16; d<<=1) v += __shfl_xor(v,d,64);
      l_i[r] = l_i[r]*alpha[r] + v;
    }
    // P: C-layout -> per-wave LDS -> A-layout (same-wave RAW, no barrier)
    unsigned short* sPw = sP + wid*16*72;
    #pragma unroll
    for (int nt=0;nt<4;nt++)
      #pragma unroll
      for (int r=0;r<4;r++)
        sPw[(quad*4+r)*72 + nt*16 + l16] = f32_to_bf16(s[nt][r]);
    short8 p0f = *(const short8*)(sPw + l16*72 + quad*8);
    short8 p1f = *(const short8*)(sPw + l16*72 + 32 + quad*8);
    #pragma unroll
    for (int nt=0;nt<4;nt++)
      #pragma unroll
      for (int r=0;r<4;r++)
        o[nt][r] *= alpha[r];
    __syncthreads();                       // sVt complete
    #pragma unroll
    for (int nt=0;nt<4;nt++){
      short8 vb0 = *(const short8*)(sVt + (nt*16+l16)*72 + quad*8);
      short8 vb1 = *(const short8*)(sVt + (nt*16+l16)*72 + 32 + quad*8);
      o[nt] = __builtin_amdgcn_mfma_f32_16x16x32_bf16(p0f, vb0, o[nt], 0,0,0);
      o[nt] = __builtin_amdgcn_mfma_f32_16x16x32_bf16(p1f, vb1, o[nt], 0,0,0);
    }
  }
  #pragma unroll
  for (int nt=0;nt<4;nt++)
    #pragma unroll
    for (int r=0;r<4;r++){
      int row = q0 + wid*16 + quad*4 + r;
      if (row == T_SEQ-1) continue;        // owned by lastrow block (race!)
      int col = h*64 + nt*16 + l16;
      out[(size_t)(b*T_SEQ + row)*1024 + col] = f32_to_bf16(o[nt][r] / l_i[r]);
    }
}

// ---------------------------------------------------------------- launch
extern "C" void kernel_launch(void* const* d_in, const int* in_sizes, int n_in,
                              void* d_out, int out_size, void* d_ws, size_t ws_size,
                              hipStream_t stream) {
  const float* x     = (const float*)d_in[0];
  const unsigned char* mask = (const unsigned char*)d_in[1];
  const float* ln1_g = (const float*)d_in[2];
  const float* ln1_b = (const float*)d_in[3];
  const float* ln2_g = (const float*)d_in[4];
  const float* ln2_b = (const float*)d_in[5];
  const float* Wq = (const float*)d_in[6];
  const float* Wk = (const float*)d_in[7];
  const float* Wv = (const float*)d_in[8];
  const float* Wo = (const float*)d_in[9];
  const float* bo = (const float*)d_in[10];
  const float* W1 = (const float*)d_in[11];
  const float* b1 = (const float*)d_in[12];
  const float* W2 = (const float*)d_in[13];
  const float* b2 = (const float*)d_in[14];
  float* out = (float*)d_out;

  char* ws = (char*)d_ws;
  unsigned short* wqkvT = (unsigned short*)(ws);              // 3072x1024 bf16
  unsigned short* woT   = (unsigned short*)(ws + 6291456);    // 1024x1024
  unsigned short* w1T   = (unsigned short*)(ws + 8388608);    // 4096x1024
  unsigned short* w2T   = (unsigned short*)(ws + 16777216);   // 1024x4096
  unsigned short* h_bf  = (unsigned short*)(ws + 25165824);   // 4096x1024 (reused as h2)
  unsigned short* qkv   = (unsigned short*)(ws + 33554432);   // 4096x3072
  unsigned short* aout  = (unsigned short*)(ws + 58720256);   // 4096x1024
  unsigned int*   mbits = (unsigned int*)(ws + 67108864);     // 2048x64 words (512 KB)
  int*            cols  = (int*)(ws + 67633152);              // 32x2048 ints (256 KB)
  int*            ncols = (int*)(ws + 67895296);              // 32 ints
  unsigned int*   rmask = (unsigned int*)(ws + 67895424);     // 32x64x64 words (512 KB)
  unsigned short* ff1   = qkv;                                // reuse: 4096x4096

  packmask<<<512,256,0,stream>>>(mask, mbits);
  build_cols<<<32,64,0,stream>>>(mbits, cols, ncols);
  build_rmask<<<32,256,0,stream>>>(mbits, cols, ncols, rmask);
  transcvt<<<dim3(32,32),256,0,stream>>>(Wq, wqkvT,               1024, 1024);
  transcvt<<<dim3(32,32),256,0,stream>>>(Wk, wqkvT + 1024*1024,   1024, 1024);
  transcvt<<<dim3(32,32),256,0,stream>>>(Wv, wqkvT + 2*1024*1024, 1024, 1024);
  transcvt<<<dim3(32,32),256,0,stream>>>(Wo, woT,                 1024, 1024);
  transcvt<<<dim3(128,32),256,0,stream>>>(W1, w1T, 1024, 4096);
  transcvt<<<dim3(32,128),256,0,stream>>>(W2, w2T, 4096, 1024);

  ln_kernel<<<4096,256,0,stream>>>(x, ln1_g, ln1_b, h_bf);
  gemm_bt<false,false,false,true><<<dim3(32,24),256,0,stream>>>(h_bf, wqkvT, qkv, nullptr, nullptr, 4096, 3072, 1024);
  attn_kernel<<<dim3(33,32),256,0,stream>>>(qkv, cols, ncols, rmask, aout);
  gemm_bt_n64<true,true,false><<<dim3(32,16),256,0,stream>>>(aout, woT, out, bo, x, 4096, 1024, 1024);
  ln_kernel<<<4096,256,0,stream>>>(out, ln2_g, ln2_b, h_bf);
  gemm_bt<true,true,false,true><<<dim3(32,32),256,0,stream>>>(h_bf, w1T, ff1, b1, nullptr, 4096, 4096, 1024);
  gemm_bt_n64<true,true,false><<<dim3(32,16),256,0,stream>>>(ff1, w2T, out, b2, out, 4096, 1024, 4096);
}

// Round 9
// 358.715 us; speedup vs baseline: 1.6072x; 1.0342x over previous
//
#include <hip/hip_runtime.h>

#define T_SEQ 2048

typedef __attribute__((ext_vector_type(8))) short short8;
typedef __attribute__((ext_vector_type(4))) float f32x4;

__device__ __forceinline__ unsigned short f32_to_bf16(float f){
  unsigned int u = __float_as_uint(f);
  u += 0x7fffu + ((u>>16)&1u);
  return (unsigned short)(u>>16);
}
__device__ __forceinline__ float bf16_to_f32(unsigned short h){
  unsigned int u = ((unsigned int)h) << 16;
  return __uint_as_float(u);
}

// async global->LDS, 16B per lane. LDS dest = wave-uniform base + lane*16.
__device__ __forceinline__ void g2l16(const void* g, void* l){
  __builtin_amdgcn_global_load_lds(
      (const __attribute__((address_space(1))) void*)g,
      (__attribute__((address_space(3))) void*)l, 16, 0, 0);
}

// call-free exact-GELU: Abramowitz-Stegun 7.1.26 erf, |eps|<=1.5e-7
__device__ __forceinline__ float gelu_exact(float v){
  float s = v * 0.70710678118f;
  float a = fabsf(s);
  float t = __builtin_amdgcn_rcpf(1.f + 0.3275911f*a);
  float p = t*(0.254829592f + t*(-0.284496736f + t*(1.421413741f +
            t*(-1.453152027f + t*1.061405429f))));
  float erf_a = 1.f - p*__expf(-a*a);
  float erf_s = (s < 0.f) ? -erf_a : erf_a;
  return 0.5f*v*(1.f + erf_s);
}

// ---------------------------------------------------------------- mask pack
__global__ __launch_bounds__(256) void packmask(const unsigned char* __restrict__ mraw,
                                                unsigned int* __restrict__ mbits){
  bool is_byte = (mraw[2049] == 1);
  int w = blockIdx.x*256 + threadIdx.x;          // word index, T*64 total
  int row = w >> 6, wc = w & 63;
  unsigned int bits = 0u;
  if (is_byte){
    const unsigned char* p = mraw + (size_t)row*T_SEQ + wc*32;
    #pragma unroll
    for (int j=0;j<32;j++) bits |= (p[j] ? 1u : 0u) << j;
  } else {
    const int* p = (const int*)mraw + (size_t)row*T_SEQ + wc*32;
    #pragma unroll
    for (int j=0;j<32;j++) bits |= (p[j] != 0 ? 1u : 0u) << j;
  }
  mbits[w] = bits;
}

// ------------------------------------------- BigBird column-list precompute
__global__ __launch_bounds__(64) void build_cols(const unsigned int* __restrict__ mbits,
                                                 int* __restrict__ cols,
                                                 int* __restrict__ ncols){
  int qt = blockIdx.x, lane = threadIdx.x;       // 64 lanes, one word each
  unsigned int w = 0;
  for (int r=0;r<64;r++){
    int row = qt*64 + r;
    if (row == T_SEQ-1) continue;                // dense last row excluded
    w |= mbits[(size_t)row*64 + lane];
  }
  int pc = __popc(w);
  int inc = pc;
  #pragma unroll
  for (int d=1; d<64; d<<=1){ int t = __shfl_up(inc, d, 64); if (lane>=d) inc += t; }
  int total = __shfl(inc, 63, 64);
  int idx = inc - pc;                            // exclusive prefix
  unsigned int ww = w;
  while (ww){ int b = __ffs(ww)-1; ww &= ww-1; cols[qt*2048 + idx++] = lane*32 + b; }
  for (int j = total + lane; j < 2048; j += 64) cols[qt*2048 + j] = -1;
  if (lane==0) ncols[qt] = (total + 63) & ~63;
}

// Remap mask bits onto gathered-column index space: rmask[qt][row][word].
__global__ __launch_bounds__(256) void build_rmask(const unsigned int* __restrict__ mbits,
                                                   const int* __restrict__ cols,
                                                   const int* __restrict__ ncols,
                                                   unsigned int* __restrict__ rmask){
  int qt = blockIdx.x, tid = threadIdx.x;
  int nw = ncols[qt] >> 5;                       // words actually used
  for (int e = tid; e < 64*nw; e += 256){
    int row = e / nw, wj = e % nw;
    const unsigned int* mrow = mbits + (size_t)(qt*64+row)*64;
    unsigned int bits = 0;
    #pragma unroll
    for (int b=0;b<32;b++){
      int j = wj*32 + b;
      int c = cols[qt*2048 + j];
      if (c >= 0) bits |= ((mrow[c>>5] >> (c&31)) & 1u) << b;
    }
    rmask[(size_t)(qt*64+row)*64 + wj] = bits;
  }
}

// ------------------------------------------------- weight transpose+convert
__global__ __launch_bounds__(256) void transcvt(const float* __restrict__ W,
                                                unsigned short* __restrict__ WT,
                                                int K, int N){
  __shared__ float tile[32][33];
  int tx = threadIdx.x & 31, ty = threadIdx.x >> 5;
  int n0 = blockIdx.x*32, k0 = blockIdx.y*32;
  #pragma unroll
  for (int j=0;j<32;j+=8)
    tile[ty+j][tx] = W[(size_t)(k0+ty+j)*N + n0 + tx];
  __syncthreads();
  #pragma unroll
  for (int j=0;j<32;j+=8)
    WT[(size_t)(n0+ty+j)*K + k0 + tx] = f32_to_bf16(tile[tx][ty+j]);
}

// ---------------------------------------------------------------- layernorm
__global__ __launch_bounds__(256) void ln_kernel(const float* __restrict__ x,
                                                 const float* __restrict__ g,
                                                 const float* __restrict__ b,
                                                 unsigned short* __restrict__ out){
  int row = blockIdx.x, tid = threadIdx.x;
  const float* xr = x + (size_t)row*1024;
  float4 xv = *(const float4*)(xr + tid*4);
  float s  = xv.x+xv.y+xv.z+xv.w;
  float s2 = xv.x*xv.x + xv.y*xv.y + xv.z*xv.z + xv.w*xv.w;
  #pragma unroll
  for (int d=1; d<64; d<<=1){ s += __shfl_xor(s,d,64); s2 += __shfl_xor(s2,d,64); }
  __shared__ float ls[4], ls2[4];
  int wid = tid >> 6;
  if ((tid & 63) == 0){ ls[wid]=s; ls2[wid]=s2; }
  __syncthreads();
  float tot = ls[0]+ls[1]+ls[2]+ls[3];
  float tot2= ls2[0]+ls2[1]+ls2[2]+ls2[3];
  float mu  = tot * (1.f/1024.f);
  float var = tot2 * (1.f/1024.f) - mu*mu;
  float inv = rsqrtf(var + 1e-5f);
  float4 gv = *(const float4*)(g + tid*4);
  float4 bv = *(const float4*)(b + tid*4);
  unsigned short o0 = f32_to_bf16((xv.x-mu)*inv*gv.x + bv.x);
  unsigned short o1 = f32_to_bf16((xv.y-mu)*inv*gv.y + bv.y);
  unsigned short o2 = f32_to_bf16((xv.z-mu)*inv*gv.z + bv.z);
  unsigned short o3 = f32_to_bf16((xv.w-mu)*inv*gv.w + bv.w);
  unsigned short* op = out + (size_t)row*1024 + tid*4;
  op[0]=o0; op[1]=o1; op[2]=o2; op[3]=o3;
}

// ------------------------------------------------------------------- GEMM
// 128x128 tile, BK=64, 3-bit XOR chunk swizzle (conflict-free b128 reads).
template<bool GELU, bool BIAS, bool RES, bool OUTBF>
__global__ __launch_bounds__(256,4) void gemm_bt(const unsigned short* __restrict__ A,
                                                 const unsigned short* __restrict__ BT,
                                                 void* __restrict__ Cout,
                                                 const float* __restrict__ bias,
                                                 const float* __restrict__ res,
                                                 int M, int N, int K){
  __shared__ unsigned short sA[128*64];
  __shared__ unsigned short sB[128*64];
  int tid = threadIdx.x;
  int m0 = blockIdx.x*128, n0 = blockIdx.y*128;
  int wid = tid>>6, lane = tid&63;
  int wm = (wid>>1)*64, wn = (wid&1)*64;
  int l16 = lane&15, quad = lane>>4;
  int qa0 = (quad     ^ (l16&7))*8;
  int qa1 = ((quad+4) ^ (l16&7))*8;

  f32x4 acc[4][4] = {};
  for (int k0=0; k0<K; k0+=64){
    #pragma unroll
    for (int i=0;i<4;i++){
      int t = i*256 + tid;                         // [0,1024)
      int row = t>>3;
      int kc = ((t&7) ^ (row&7))*8;
      int wb = i*256 + (tid & ~63);
      g2l16(A  + (size_t)(m0+row)*K + k0 + kc, sA + wb*8);
      g2l16(BT + (size_t)(n0+row)*K + k0 + kc, sB + wb*8);
    }
    __syncthreads();
    #pragma unroll
    for (int kk=0;kk<2;kk++){
      int qa = kk ? qa1 : qa0;
      short8 af[4], bf[4];
      #pragma unroll
      for (int mi=0;mi<4;mi++) af[mi] = *(const short8*)(sA + (wm+mi*16+l16)*64 + qa);
      #pragma unroll
      for (int ni=0;ni<4;ni++) bf[ni] = *(const short8*)(sB + (wn+ni*16+l16)*64 + qa);
      #pragma unroll
      for (int mi=0;mi<4;mi++)
        #pragma unroll
        for (int ni=0;ni<4;ni++)
          acc[mi][ni] = __builtin_amdgcn_mfma_f32_16x16x32_bf16(af[mi], bf[ni], acc[mi][ni], 0,0,0);
    }
    __syncthreads();
  }
  #pragma unroll
  for (int mi=0;mi<4;mi++)
    #pragma unroll
    for (int ni=0;ni<4;ni++){
      int col = n0 + wn + ni*16 + l16;
      float bval = 0.f;
      if constexpr (BIAS) bval = bias[col];
      #pragma unroll
      for (int r=0;r<4;r++){
        int row = m0 + wm + mi*16 + quad*4 + r;
        float v = acc[mi][ni][r] + bval;
        if constexpr (GELU) v = gelu_exact(v);
        if constexpr (RES)  v += res[(size_t)row*N + col];
        if constexpr (OUTBF) ((unsigned short*)Cout)[(size_t)row*N + col] = f32_to_bf16(v);
        else                 ((float*)Cout)[(size_t)row*N + col] = v;
      }
    }
}

// Split-K 128x128 tile: blockIdx.z selects K-half; partials atomicAdd'ed
// into f32 Cout (which must already hold the residual). z==0 adds bias.
template<bool BIAS>
__global__ __launch_bounds__(256,4) void gemm_bt_splitk(const unsigned short* __restrict__ A,
                                                        const unsigned short* __restrict__ BT,
                                                        float* __restrict__ Cout,
                                                        const float* __restrict__ bias,
                                                        int M, int N, int K){
  __shared__ unsigned short sA[128*64];
  __shared__ unsigned short sB[128*64];
  int tid = threadIdx.x;
  int m0 = blockIdx.x*128, n0 = blockIdx.y*128;
  int kbeg = blockIdx.z * (K>>1), kend = kbeg + (K>>1);
  int wid = tid>>6, lane = tid&63;
  int wm = (wid>>1)*64, wn = (wid&1)*64;
  int l16 = lane&15, quad = lane>>4;
  int qa0 = (quad     ^ (l16&7))*8;
  int qa1 = ((quad+4) ^ (l16&7))*8;

  f32x4 acc[4][4] = {};
  for (int k0=kbeg; k0<kend; k0+=64){
    #pragma unroll
    for (int i=0;i<4;i++){
      int t = i*256 + tid;
      int row = t>>3;
      int kc = ((t&7) ^ (row&7))*8;
      int wb = i*256 + (tid & ~63);
      g2l16(A  + (size_t)(m0+row)*K + k0 + kc, sA + wb*8);
      g2l16(BT + (size_t)(n0+row)*K + k0 + kc, sB + wb*8);
    }
    __syncthreads();
    #pragma unroll
    for (int kk=0;kk<2;kk++){
      int qa = kk ? qa1 : qa0;
      short8 af[4], bf[4];
      #pragma unroll
      for (int mi=0;mi<4;mi++) af[mi] = *(const short8*)(sA + (wm+mi*16+l16)*64 + qa);
      #pragma unroll
      for (int ni=0;ni<4;ni++) bf[ni] = *(const short8*)(sB + (wn+ni*16+l16)*64 + qa);
      #pragma unroll
      for (int mi=0;mi<4;mi++)
        #pragma unroll
        for (int ni=0;ni<4;ni++)
          acc[mi][ni] = __builtin_amdgcn_mfma_f32_16x16x32_bf16(af[mi], bf[ni], acc[mi][ni], 0,0,0);
    }
    __syncthreads();
  }
  #pragma unroll
  for (int mi=0;mi<4;mi++)
    #pragma unroll
    for (int ni=0;ni<4;ni++){
      int col = n0 + wn + ni*16 + l16;
      float bval = 0.f;
      if constexpr (BIAS) { if (blockIdx.z == 0) bval = bias[col]; }
      #pragma unroll
      for (int r=0;r<4;r++){
        int row = m0 + wm + mi*16 + quad*4 + r;
        atomicAdd(&Cout[(size_t)row*N + col], acc[mi][ni][r] + bval);
      }
    }
}

// 128x64-tile, BK=64 variant for N=1024 outputs (512 blocks -> 2/CU).
template<bool BIAS, bool RES, bool OUTBF>
__global__ __launch_bounds__(256,2) void gemm_bt_n64(const unsigned short* __restrict__ A,
                                                     const unsigned short* __restrict__ BT,
                                                     void* __restrict__ Cout,
                                                     const float* __restrict__ bias,
                                                     const float* __restrict__ res,
                                                     int M, int N, int K){
  __shared__ unsigned short sA[128*64];
  __shared__ unsigned short sB[64*64];
  int tid = threadIdx.x;
  int m0 = blockIdx.x*128, n0 = blockIdx.y*64;
  int wid = tid>>6, lane = tid&63;
  int wm = (wid>>1)*64, wn = (wid&1)*32;
  int l16 = lane&15, quad = lane>>4;
  int qa0 = (quad     ^ (l16&7))*8;   // k-slice 0 read chunk
  int qa1 = ((quad+4) ^ (l16&7))*8;   // k-slice 1 read chunk

  f32x4 acc[4][2] = {};
  for (int k0=0; k0<K; k0+=64){
    #pragma unroll
    for (int i=0;i<4;i++){
      int t = i*256 + tid;                         // [0,1024)
      int row = t>>3;
      int kc = ((t&7) ^ (row&7))*8;
      int wb = i*256 + (tid & ~63);
      g2l16(A + (size_t)(m0+row)*K + k0 + kc, sA + wb*8);
    }
    #pragma unroll
    for (int i=0;i<2;i++){
      int t = i*256 + tid;                         // [0,512)
      int row = t>>3;
      int kc = ((t&7) ^ (row&7))*8;
      int wb = i*256 + (tid & ~63);
      g2l16(BT + (size_t)(n0+row)*K + k0 + kc, sB + wb*8);
    }
    __syncthreads();
    #pragma unroll
    for (int kk=0;kk<2;kk++){
      int qa = kk ? qa1 : qa0;
      short8 af[4], bf[2];
      #pragma unroll
      for (int mi=0;mi<4;mi++) af[mi] = *(const short8*)(sA + (wm+mi*16+l16)*64 + qa);
      #pragma unroll
      for (int ni=0;ni<2;ni++) bf[ni] = *(const short8*)(sB + (wn+ni*16+l16)*64 + qa);
      #pragma unroll
      for (int mi=0;mi<4;mi++)
        #pragma unroll
        for (int ni=0;ni<2;ni++)
          acc[mi][ni] = __builtin_amdgcn_mfma_f32_16x16x32_bf16(af[mi], bf[ni], acc[mi][ni], 0,0,0);
    }
    __syncthreads();
  }
  #pragma unroll
  for (int mi=0;mi<4;mi++)
    #pragma unroll
    for (int ni=0;ni<2;ni++){
      int col = n0 + wn + ni*16 + l16;
      float bval = 0.f;
      if constexpr (BIAS) bval = bias[col];
      #pragma unroll
      for (int r=0;r<4;r++){
        int row = m0 + wm + mi*16 + quad*4 + r;
        float v = acc[mi][ni][r] + bval;
        if constexpr (RES)  v += res[(size_t)row*N + col];
        if constexpr (OUTBF) ((unsigned short*)Cout)[(size_t)row*N + col] = f32_to_bf16(v);
        else                 ((float*)Cout)[(size_t)row*N + col] = v;
      }
    }
}

// ------------------------------------------------------------- attention
// grid (33, 32): x<32 -> sparse-gather flash attention for q-tile 31-x;
// x==32 -> dense last-row (row T-1) attention, vectorized two-pass softmax.
__global__ __launch_bounds__(256,4) void attn_kernel(const unsigned short* __restrict__ qkv,
                                                     const int* __restrict__ cols,
                                                     const int* __restrict__ ncols,
                                                     const unsigned int* __restrict__ rmask,
                                                     unsigned short* __restrict__ out){
  __shared__ __align__(16) char smem[36864];
  int bh = blockIdx.y;                // 0..31
  int b = bh >> 4, h = bh & 15;
  int tid = threadIdx.x, wid = tid>>6, lane = tid&63;
  const int RS = 3072;
  const size_t base = (size_t)b * T_SEQ * RS;

  if (blockIdx.x == 32){
    // ---------------- dense last row ----------------
    float* sS  = (float*)smem;                      // 2048 f32
    float* sOr = (float*)(smem + 8192);             // 32 x 65 f32 (padded)
    float* sRed= (float*)(smem + 16512);            // 8 f32
    unsigned short* sQ = (unsigned short*)(smem + 16544); // 64 bf16

    if (tid < 8)
      ((uint4*)sQ)[tid] = *(const uint4*)(qkv + base + (size_t)(T_SEQ-1)*RS + h*64 + tid*8);
    __syncthreads();
    unsigned short q16[64];
    #pragma unroll
    for (int c=0;c<8;c++) *(uint4*)(q16 + c*8) = ((const uint4*)sQ)[c];

    float lmax = -1e30f;
    #pragma unroll
    for (int i=0;i<8;i++){
      int k = tid + 256*i;
      const unsigned short* kp = qkv + base + (size_t)k*RS + 1024 + h*64;
      float acc = 0.f;
      #pragma unroll
      for (int c=0;c<8;c++){
        unsigned short kk[8];
        *(uint4*)kk = *(const uint4*)(kp + c*8);
        #pragma unroll
        for (int j=0;j<8;j++) acc += bf16_to_f32(q16[c*8+j])*bf16_to_f32(kk[j]);
      }
      float sv = acc * 0.125f;
      sS[k] = sv;
      lmax = fmaxf(lmax, sv);
    }
    #pragma unroll
    for (int d=1; d<64; d<<=1) lmax = fmaxf(lmax, __shfl_xor(lmax, d, 64));
    if (lane == 0) sRed[wid] = lmax;
    __syncthreads();
    float m = fmaxf(fmaxf(sRed[0],sRed[1]), fmaxf(sRed[2],sRed[3]));
    float lsum = 0.f;
    #pragma unroll
    for (int i=0;i<8;i++){
      int k = tid + 256*i;
      float p = __expf(sS[k] - m);
      sS[k] = p;
      lsum += p;
    }
    #pragma unroll
    for (int d=1; d<64; d<<=1) lsum += __shfl_xor(lsum, d, 64);
    if (lane == 0) sRed[4+wid] = lsum;
    __syncthreads();
    float l = sRed[4]+sRed[5]+sRed[6]+sRed[7];

    int dg = tid & 7, kl = tid >> 3;
    float o8[8] = {};
    const unsigned short* vbase = qkv + base + 2048 + h*64 + dg*8;
    #pragma unroll 4
    for (int i=0;i<64;i++){
      int k = kl + 32*i;
      float p = sS[k];
      unsigned short vv[8];
      *(uint4*)vv = *(const uint4*)(vbase + (size_t)k*RS);
      #pragma unroll
      for (int j=0;j<8;j++) o8[j] += p * bf16_to_f32(vv[j]);
    }
    #pragma unroll
    for (int j=0;j<8;j++) sOr[kl*65 + dg*8 + j] = o8[j];
    __syncthreads();
    if (tid < 64){
      float s = 0.f;
      #pragma unroll
      for (int k2=0;k2<32;k2++) s += sOr[k2*65 + tid];
      out[(size_t)(b*T_SEQ + T_SEQ-1)*1024 + h*64 + tid] = f32_to_bf16(s / l);
    }
    return;
  }

  // ---------------- sparse q-tiles ----------------
  unsigned short* sK  = (unsigned short*)smem;            // [64][72]
  unsigned short* sVt = (unsigned short*)(smem +  9216);  // [64][72]
  unsigned short* sX  = (unsigned short*)(smem + 18432);  // [64][72]
  unsigned short* sP  = (unsigned short*)(smem + 27648);  // [4][16][72]

  int qt = 31 - blockIdx.x;
  int l16 = lane&15, quad = lane>>4;
  int q0 = qt*64;

  const int* gcols = cols + qt*2048;
  int niter = ncols[qt] >> 6;

  int qrow = q0 + wid*16 + l16;
  const unsigned short* qptr = qkv + base + (size_t)qrow*RS + h*64;
  short8 qf0 = *(const short8*)(qptr + quad*8);
  short8 qf1 = *(const short8*)(qptr + 32 + quad*8);

  f32x4 o[4] = {};
  float m_i[4], l_i[4];
  #pragma unroll
  for (int r=0;r<4;r++){ m_i[r] = -1e30f; l_i[r] = 0.f; }

  int krow0 = tid>>3, krow1 = 32 + (tid>>3), dc = (tid&7)*8;
  int c0n = gcols[krow0], c1n = gcols[krow1];

  for (int kt=0; kt<niter; ++kt){
    int c0 = c0n < 0 ? 0 : c0n;
    int c1 = c1n < 0 ? 0 : c1n;
    const unsigned short* p0 = qkv + base + (size_t)c0*RS + 1024 + h*64 + dc;
    const unsigned short* p1 = qkv + base + (size_t)c1*RS + 1024 + h*64 + dc;
    uint4 k0 = *(const uint4*)p0;
    uint4 k1 = *(const uint4*)p1;
    uint4 v0 = *(const uint4*)(p0 + 1024);
    uint4 v1 = *(const uint4*)(p1 + 1024);
    if (kt+1 < niter){
      c0n = gcols[(kt+1)*64 + krow0];
      c1n = gcols[(kt+1)*64 + krow1];
    }
    __syncthreads();                       // prev iter's LDS readers done
    *(uint4*)(sK + krow0*72 + dc) = k0;
    *(uint4*)(sK + krow1*72 + dc) = k1;
    *(uint4*)(sX + krow0*72 + dc) = v0;
    *(uint4*)(sX + krow1*72 + dc) = v1;
    __syncthreads();                       // sK/sX visible

    // transpose sX -> sVt (krow lane-fast => conflict-free)
    #pragma unroll
    for (int pass=0; pass<2; ++pass){
      int dg = pass*4 + wid;
      unsigned short v8[8];
      *(uint4*)v8 = *(const uint4*)(sX + lane*72 + dg*8);
      #pragma unroll
      for (int j=0;j<8;j++) sVt[(dg*8+j)*72 + lane] = v8[j];
    }

    // S = Q @ K^T
    f32x4 s[4];
    #pragma unroll
    for (int nt=0;nt<4;nt++){
      f32x4 z = {};
      short8 kb0 = *(const short8*)(sK + (nt*16+l16)*72 + quad*8);
      short8 kb1 = *(const short8*)(sK + (nt*16+l16)*72 + 32 + quad*8);
      z = __builtin_amdgcn_mfma_f32_16x16x32_bf16(qf0, kb0, z, 0,0,0);
      z = __builtin_amdgcn_mfma_f32_16x16x32_bf16(qf1, kb1, z, 0,0,0);
      s[nt] = z;
    }

    // mask (remapped bits) + scale
    float rowmax[4];
    #pragma unroll
    for (int r=0;r<4;r++){
      int rowin = wid*16 + quad*4 + r;
      const unsigned int* mrow = rmask + (size_t)(qt*64+rowin)*64 + kt*2;
      unsigned long long m64 = (unsigned long long)mrow[0] |
                               ((unsigned long long)mrow[1] << 32);
      float rm = -1e30f;
      #pragma unroll
      for (int nt=0;nt<4;nt++){
        int c6 = nt*16 + l16;
        bool ok = (m64 >> c6) & 1ull;
        float v = ok ? s[nt][r]*0.125f : -1e30f;
        s[nt][r] = v;
        rm = fmaxf(rm, v);
      }
      rowmax[r] = rm;
    }
    #pragma unroll
    for (int r=0;r<4;r++){
      float v = rowmax[r];
      #pragma unroll
      for (int d=1; d<16; d<<=1) v = fmaxf(v, __shfl_xor(v,d,64));
      rowmax[r] = v;
    }
    float alpha[4];
    #pragma unroll
    for (int r=0;r<4;r++){
      float mnew = fmaxf(m_i[r], rowmax[r]);
      alpha[r] = __expf(m_i[r] - mnew);
      m_i[r] = mnew;
    }
    #pragma unroll
    for (int nt=0;nt<4;nt++)
      #pragma unroll
      for (int r=0;r<4;r++)
        s[nt][r] = __expf(s[nt][r] - m_i[r]);
    #pragma unroll
    for (int r=0;r<4;r++){
      float v = s[0][r]+s[1][r]+s[2][r]+s[3][r];
      #pragma unroll
      for (int d=1; d<16; d<<=1) v += __shfl_xor(v,d,64);
      l_i[r] = l_i[r]*alpha[r] + v;
    }
    // P: C-layout -> per-wave LDS -> A-layout (same-wave RAW, no barrier)
    unsigned short* sPw = sP + wid*16*72;
    #pragma unroll
    for (int nt=0;nt<4;nt++)
      #pragma unroll
      for (int r=0;r<4;r++)
        sPw[(quad*4+r)*72 + nt*16 + l16] = f32_to_bf16(s[nt][r]);
    short8 p0f = *(const short8*)(sPw + l16*72 + quad*8);
    short8 p1f = *(const short8*)(sPw + l16*72 + 32 + quad*8);
    #pragma unroll
    for (int nt=0;nt<4;nt++)
      #pragma unroll
      for (int r=0;r<4;r++)
        o[nt][r] *= alpha[r];
    __syncthreads();                       // sVt complete
    #pragma unroll
    for (int nt=0;nt<4;nt++){
      short8 vb0 = *(const short8*)(sVt + (nt*16+l16)*72 + quad*8);
      short8 vb1 = *(const short8*)(sVt + (nt*16+l16)*72 + 32 + quad*8);
      o[nt] = __builtin_amdgcn_mfma_f32_16x16x32_bf16(p0f, vb0, o[nt], 0,0,0);
      o[nt] = __builtin_amdgcn_mfma_f32_16x16x32_bf16(p1f, vb1, o[nt], 0,0,0);
    }
  }
  #pragma unroll
  for (int nt=0;nt<4;nt++)
    #pragma unroll
    for (int r=0;r<4;r++){
      int row = q0 + wid*16 + quad*4 + r;
      if (row == T_SEQ-1) continue;        // owned by lastrow block (race!)
      int col = h*64 + nt*16 + l16;
      out[(size_t)(b*T_SEQ + row)*1024 + col] = f32_to_bf16(o[nt][r] / l_i[r]);
    }
}

// ---------------------------------------------------------------- launch
extern "C" void kernel_launch(void* const* d_in, const int* in_sizes, int n_in,
                              void* d_out, int out_size, void* d_ws, size_t ws_size,
                              hipStream_t stream) {
  const float* x     = (const float*)d_in[0];
  const unsigned char* mask = (const unsigned char*)d_in[1];
  const float* ln1_g = (const float*)d_in[2];
  const float* ln1_b = (const float*)d_in[3];
  const float* ln2_g = (const float*)d_in[4];
  const float* ln2_b = (const float*)d_in[5];
  const float* Wq = (const float*)d_in[6];
  const float* Wk = (const float*)d_in[7];
  const float* Wv = (const float*)d_in[8];
  const float* Wo = (const float*)d_in[9];
  const float* bo = (const float*)d_in[10];
  const float* W1 = (const float*)d_in[11];
  const float* b1 = (const float*)d_in[12];
  const float* W2 = (const float*)d_in[13];
  const float* b2 = (const float*)d_in[14];
  float* out = (float*)d_out;

  char* ws = (char*)d_ws;
  unsigned short* wqkvT = (unsigned short*)(ws);              // 3072x1024 bf16
  unsigned short* woT   = (unsigned short*)(ws + 6291456);    // 1024x1024
  unsigned short* w1T   = (unsigned short*)(ws + 8388608);    // 4096x1024
  unsigned short* w2T   = (unsigned short*)(ws + 16777216);   // 1024x4096
  unsigned short* h_bf  = (unsigned short*)(ws + 25165824);   // 4096x1024 (reused as h2)
  unsigned short* qkv   = (unsigned short*)(ws + 33554432);   // 4096x3072
  unsigned short* aout  = (unsigned short*)(ws + 58720256);   // 4096x1024
  unsigned int*   mbits = (unsigned int*)(ws + 67108864);     // 2048x64 words (512 KB)
  int*            cols  = (int*)(ws + 67633152);              // 32x2048 ints (256 KB)
  int*            ncols = (int*)(ws + 67895296);              // 32 ints
  unsigned int*   rmask = (unsigned int*)(ws + 67895424);     // 32x64x64 words (512 KB)
  unsigned short* ff1   = qkv;                                // reuse: 4096x4096

  packmask<<<512,256,0,stream>>>(mask, mbits);
  build_cols<<<32,64,0,stream>>>(mbits, cols, ncols);
  build_rmask<<<32,256,0,stream>>>(mbits, cols, ncols, rmask);
  transcvt<<<dim3(32,32),256,0,stream>>>(Wq, wqkvT,               1024, 1024);
  transcvt<<<dim3(32,32),256,0,stream>>>(Wk, wqkvT + 1024*1024,   1024, 1024);
  transcvt<<<dim3(32,32),256,0,stream>>>(Wv, wqkvT + 2*1024*1024, 1024, 1024);
  transcvt<<<dim3(32,32),256,0,stream>>>(Wo, woT,                 1024, 1024);
  transcvt<<<dim3(128,32),256,0,stream>>>(W1, w1T, 1024, 4096);
  transcvt<<<dim3(32,128),256,0,stream>>>(W2, w2T, 4096, 1024);

  ln_kernel<<<4096,256,0,stream>>>(x, ln1_g, ln1_b, h_bf);
  gemm_bt<false,false,false,true><<<dim3(32,24),256,0,stream>>>(h_bf, wqkvT, qkv, nullptr, nullptr, 4096, 3072, 1024);
  attn_kernel<<<dim3(33,32),256,0,stream>>>(qkv, cols, ncols, rmask, aout);
  gemm_bt_n64<true,true,false><<<dim3(32,16),256,0,stream>>>(aout, woT, out, bo, x, 4096, 1024, 1024);
  ln_kernel<<<4096,256,0,stream>>>(out, ln2_g, ln2_b, h_bf);
  gemm_bt<true,true,false,true><<<dim3(32,32),256,0,stream>>>(h_bf, w1T, ff1, b1, nullptr, 4096, 4096, 1024);
  // ff2: split-K=2, partials atomically accumulated into out (holds residual x2)
  gemm_bt_splitk<true><<<dim3(32,8,2),256,0,stream>>>(ff1, w2T, out, b2, 4096, 1024, 4096);
}